// Round 2
// baseline (2297.395 us; speedup 1.0000x reference)
//
#include <hip/hip_runtime.h>
#include <math.h>

typedef __bf16 bf16;
typedef __bf16 bf16x8 __attribute__((ext_vector_type(8)));
typedef float f32x4 __attribute__((ext_vector_type(4)));

#define DEVI static __device__ __forceinline__

DEVI float b2f(bf16 x){ return (float)x; }
DEVI bf16  f2b(float x){ return (bf16)x; }
DEVI float siluf_(float x){ return x / (1.f + __expf(-x)); }

DEVI void gload_lds16(const void* g, void* l){
  __builtin_amdgcn_global_load_lds((const __attribute__((address_space(1))) void*)g,
                                   (__attribute__((address_space(3))) void*)l, 16, 0, 0);
}

// ---------------------------------------------------------------------------
// C = A * W^T, A (M x K) bf16 row-major (lda), W (N x K) bf16 row-major (ldw).
// 128x128 tile, BK=64, 4 waves (2x2), 16x16x32 bf16 MFMA, global_load_lds.
// Epilogues: 0 bf16 | 1 fp32 | 2 softplus(acc+aux[col])->bf16
//            3 fp32 acc+aux[idx] | 4 C=silu(C)*acc (bf16, in place) | 5 C+=acc (fp32)
// ---------------------------------------------------------------------------
template<int EPI>
__global__ __launch_bounds__(256)
void gemm_bt(const bf16* __restrict__ A, int lda,
             const bf16* __restrict__ W, int ldw,
             void* __restrict__ Cp, int ldc,
             const float* __restrict__ aux, int K)
{
  __shared__ __align__(16) bf16 As[128*64];
  __shared__ __align__(16) bf16 Bs[128*64];
  const int tid  = threadIdx.x;
  const int lane = tid & 63;
  const int wid  = tid >> 6;
  const int srow = tid >> 3;          // 0..31
  const int scol = (tid & 7) << 3;    // 0..56

  const bf16* Ag = A + (long)blockIdx.x*128*lda + (long)srow*lda + scol;
  const bf16* Wg = W + (long)blockIdx.y*128*ldw + (long)srow*ldw + scol;
  bf16* Asd = &As[tid*8];
  bf16* Bsd = &Bs[tid*8];

  f32x4 acc[4][4];
#pragma unroll
  for (int i2=0;i2<4;i2++)
#pragma unroll
    for (int j2=0;j2<4;j2++) acc[i2][j2] = {0.f,0.f,0.f,0.f};

  const int wr = (wid>>1)<<6;
  const int wc = (wid&1)<<6;
  const int fr = lane & 15;
  const int fq = lane >> 4;

  for (int k0=0; k0<K; k0+=64){
    __syncthreads();
#pragma unroll
    for (int is=0; is<4; is++){
      gload_lds16(Ag + (long)is*32*lda + k0, Asd + is*2048);
      gload_lds16(Wg + (long)is*32*ldw + k0, Bsd + is*2048);
    }
    __syncthreads();
#pragma unroll
    for (int kk=0; kk<2; kk++){
      bf16x8 av[4], bv[4];
#pragma unroll
      for (int mi=0; mi<4; mi++)
        av[mi] = *(const bf16x8*)&As[(wr + mi*16 + fr)*64 + kk*32 + fq*8];
#pragma unroll
      for (int nj=0; nj<4; nj++)
        bv[nj] = *(const bf16x8*)&Bs[(wc + nj*16 + fr)*64 + kk*32 + fq*8];
#pragma unroll
      for (int mi=0; mi<4; mi++)
#pragma unroll
        for (int nj=0; nj<4; nj++)
          acc[mi][nj] = __builtin_amdgcn_mfma_f32_16x16x32_bf16(av[mi], bv[nj], acc[mi][nj], 0, 0, 0);
    }
  }

  const int row0 = (blockIdx.x<<7) + wr + (fq<<2);
  const int col0 = (blockIdx.y<<7) + wc + fr;
#pragma unroll
  for (int mi=0; mi<4; mi++){
#pragma unroll
    for (int nj=0; nj<4; nj++){
#pragma unroll
      for (int r=0; r<4; r++){
        const int row = row0 + mi*16 + r;
        const int col = col0 + nj*16;
        const long idx = (long)row*ldc + col;
        const float v = acc[mi][nj][r];
        if constexpr (EPI==0){ ((bf16*)Cp)[idx] = f2b(v); }
        else if constexpr (EPI==1){ ((float*)Cp)[idx] = v; }
        else if constexpr (EPI==2){
          float t = v + aux[col];
          ((bf16*)Cp)[idx] = f2b(t > 20.f ? t : log1pf(__expf(t)));
        }
        else if constexpr (EPI==3){ ((float*)Cp)[idx] = v + aux[idx]; }
        else if constexpr (EPI==4){
          bf16* g = (bf16*)Cp;
          g[idx] = f2b(siluf_(b2f(g[idx])) * v);
        }
        else { float* o = (float*)Cp; o[idx] += v; }
      }
    }
  }
}

__global__ void k_convert(const float* __restrict__ src, bf16* __restrict__ dst,
                          int n_dst, int n_src){
  int i = blockIdx.x*256 + threadIdx.x;
  if (i < n_dst) dst[i] = (i < n_src) ? f2b(src[i]) : f2b(0.f);
}

// RMSNorm over rows of 1024 fp32 -> bf16
__global__ __launch_bounds__(256)
void k_rmsnorm(const float* __restrict__ x, const float* __restrict__ w,
               bf16* __restrict__ out){
  const int row = blockIdx.x;
  const float4 v = ((const float4*)(x + (long)row*1024))[threadIdx.x];
  float ss = v.x*v.x + v.y*v.y + v.z*v.z + v.w*v.w;
#pragma unroll
  for (int off=32; off; off>>=1) ss += __shfl_down(ss, off);
  __shared__ float ps[4];
  if ((threadIdx.x & 63) == 0) ps[threadIdx.x>>6] = ss;
  __syncthreads();
  const float tot = ps[0]+ps[1]+ps[2]+ps[3];
  const float scale = rsqrtf(tot*(1.f/1024.f) + 1e-5f);
  const float4 wv = ((const float4*)w)[threadIdx.x];
  bf16* o = out + (long)row*1024 + threadIdx.x*4;
  o[0]=f2b(v.x*scale*wv.x); o[1]=f2b(v.y*scale*wv.y);
  o[2]=f2b(v.z*scale*wv.z); o[3]=f2b(v.w*scale*wv.w);
}

// causal depthwise conv (K=4) + bias + SiLU over xiraw (BT x 2048)
__global__ __launch_bounds__(256)
void k_conv(const bf16* __restrict__ xiraw, const float* __restrict__ cw,
            const float* __restrict__ cb, bf16* __restrict__ out){
  const long gid = (long)blockIdx.x*256 + threadIdx.x;   // BT*I
  const int i = (int)(gid & 2047);
  const long rowg = gid >> 11;
  const int t = (int)(rowg & 2047);
  float acc = cb[i];
#pragma unroll
  for (int k=0;k<4;k++){
    const int tt = t + k - 3;
    if (tt >= 0)
      acc = fmaf(b2f(xiraw[(rowg + k - 3)*2048 + i]), cw[i*4+k], acc);
  }
  out[gid] = f2b(siluf_(acc));
}

// sp[:, 0:64] fp32 -> bf16
__global__ void k_dtr(const float* __restrict__ sp, bf16* __restrict__ dtr){
  int idx = blockIdx.x*256 + threadIdx.x;   // BT*64
  dtr[idx] = f2b(sp[(long)(idx>>6)*128 + (idx&63)]);
}

// SSM scan with fused gating epilogue. xiy holds xi on input, final y on output.
__global__ __launch_bounds__(64)
void k_scan(const bf16* __restrict__ dt, bf16* __restrict__ xiy,
            const float* __restrict__ sp, const float* __restrict__ A_log,
            const bf16* __restrict__ gate, const float* __restrict__ Dw)
{
  const int tid = threadIdx.x;
  const int b = blockIdx.x >> 5;
  const int i = ((blockIdx.x & 31) << 6) + tid;
  const float Di = Dw[i];
  float Ar[16], s[16];
#pragma unroll
  for (int n=0;n<16;n++){ Ar[n] = -__expf(A_log[i*16+n]); s[n]=0.f; }
  __shared__ float BCs[64][32];
  for (int tc=0; tc<32; tc++){
    const int rowbase = b*2048 + tc*64;
    __syncthreads();
#pragma unroll
    for (int j=0;j<32;j++){
      const int idx = (j<<6) + tid;
      BCs[idx>>5][idx&31] = sp[(long)(rowbase + (idx>>5))*128 + 64 + (idx&31)];
    }
    __syncthreads();
    for (int tt=0; tt<64; tt+=4){
      float dtv[4], xv[4], gv[4];
#pragma unroll
      for (int j2=0;j2<4;j2++){
        const long g = (long)(rowbase+tt+j2)*2048 + i;
        dtv[j2] = b2f(dt[g]); xv[j2] = b2f(xiy[g]); gv[j2] = b2f(gate[g]);
      }
#pragma unroll
      for (int j2=0;j2<4;j2++){
        const float dx = dtv[j2]*xv[j2];
        float yv = 0.f;
#pragma unroll
        for (int n=0;n<16;n++){
          const float dA = __expf(dtv[j2]*Ar[n]);
          s[n] = fmaf(dA, s[n], dx*BCs[tt+j2][n]);
          yv = fmaf(s[n], BCs[tt+j2][16+n], yv);
        }
        xiy[(long)(rowbase+tt+j2)*2048 + i] = f2b((yv + xv[j2]*Di) * siluf_(gv[j2]));
      }
    }
  }
}

extern "C" void kernel_launch(void* const* d_in, const int* in_sizes, int n_in,
                              void* d_out, int out_size, void* d_ws, size_t ws_size,
                              hipStream_t stream)
{
  const float* x         = (const float*)d_in[0];
  const float* mixer_w   = (const float*)d_in[1];
  const float* in_proj_w = (const float*)d_in[2];
  const float* conv_w    = (const float*)d_in[3];
  const float* conv_b    = (const float*)d_in[4];
  const float* x_proj_w  = (const float*)d_in[5];
  const float* dt_proj_w = (const float*)d_in[6];
  const float* dt_proj_b = (const float*)d_in[7];
  const float* A_log     = (const float*)d_in[8];
  const float* Dv        = (const float*)d_in[9];
  const float* out_proj_w= (const float*)d_in[10];
  const float* mlp_w     = (const float*)d_in[11];
  const float* gate_w    = (const float*)d_in[12];
  const float* up_w      = (const float*)d_in[13];
  const float* down_w    = (const float*)d_in[14];
  float* outp = (float*)d_out;

  char* p = (char*)d_ws;
  auto alloc = [&](size_t n){ char* r = p; p += (n + 255) & ~(size_t)255; return (void*)r; };
  bf16* wb_in   = (bf16*)alloc((size_t)4096*1024*2);
  bf16* wb_xp   = (bf16*)alloc((size_t)128*2048*2);
  bf16* wb_dt   = (bf16*)alloc((size_t)2048*64*2);
  bf16* wb_out  = (bf16*)alloc((size_t)1024*2048*2);
  bf16* wb_gate = (bf16*)alloc((size_t)2816*1024*2);
  bf16* wb_up   = (bf16*)alloc((size_t)2816*1024*2);
  bf16* wb_down = (bf16*)alloc((size_t)1024*2816*2);
  char* r1      = (char*)alloc((size_t)32<<20);   // xb | sp+dtr
  char* r2      = (char*)alloc((size_t)64<<20);   // xiraw | dtb
  char* r3      = (char*)alloc((size_t)64<<20);   // gateb | gbuf[0:64M)
  char* r4      = (char*)alloc((size_t)64<<20);   // xiconv->y | gbuf[64M:88M)
  if ((size_t)(p - (char*)d_ws) > ws_size) return;  // diagnostic guard

  bf16*  xb     = (bf16*)r1;
  float* sp     = (float*)r1;                       // 8 MB (after xb is dead)
  bf16*  dtr    = (bf16*)(r1 + (8<<20));            // 2 MB
  bf16*  xiraw  = (bf16*)r2;
  bf16*  dtb    = (bf16*)r2;
  bf16*  gateb  = (bf16*)r3;
  bf16*  xiconv = (bf16*)r4;
  bf16*  gbuf   = (bf16*)r3;                        // 88 MB spans r3+r4

  auto cv = [&](const float* s_, bf16* d_, int nd, int ns){
    k_convert<<<dim3((nd+255)/256), dim3(256), 0, stream>>>(s_, d_, nd, ns);
  };
  cv(in_proj_w,  wb_in,   4096*1024, 4096*1024);
  cv(x_proj_w,   wb_xp,   128*2048,  96*2048);
  cv(dt_proj_w,  wb_dt,   2048*64,   2048*64);
  cv(out_proj_w, wb_out,  1024*2048, 1024*2048);
  cv(gate_w,     wb_gate, 2816*1024, 2816*1024);
  cv(up_w,       wb_up,   2816*1024, 2816*1024);
  cv(down_w,     wb_down, 1024*2816, 1024*2816);

  // 1. h = rmsnorm(x)
  k_rmsnorm<<<16384, 256, 0, stream>>>(x, mixer_w, xb);
  // 2. xi / gate halves of in_proj
  gemm_bt<0><<<dim3(128,16), 256, 0, stream>>>(xb, 1024, wb_in,             1024, xiraw, 2048, nullptr, 1024);
  gemm_bt<0><<<dim3(128,16), 256, 0, stream>>>(xb, 1024, wb_in + 2048*1024, 1024, gateb, 2048, nullptr, 1024);
  // 3. conv + silu
  k_conv<<<131072, 256, 0, stream>>>(xiraw, conv_w, conv_b, xiconv);
  // 4. sp = xiconv @ x_proj^T (padded to 128, fp32)
  gemm_bt<1><<<dim3(128,1), 256, 0, stream>>>(xiconv, 2048, wb_xp, 2048, sp, 128, nullptr, 2048);
  // 5. dt_r
  k_dtr<<<4096, 256, 0, stream>>>(sp, dtr);
  // 6. dt = softplus(dt_r @ dt_proj^T + b)
  gemm_bt<2><<<dim3(128,16), 256, 0, stream>>>(dtr, 64, wb_dt, 64, dtb, 2048, dt_proj_b, 64);
  // 7. scan + fused (y + xi*D)*silu(gate), y in place of xiconv
  k_scan<<<256, 64, 0, stream>>>(dtb, xiconv, sp, A_log, gateb, Dv);
  // 8. x2 = x + y @ out_proj^T -> d_out
  gemm_bt<3><<<dim3(128,8), 256, 0, stream>>>(xiconv, 2048, wb_out, 2048, outp, 1024, x, 2048);
  // 9. h2 = rmsnorm(x2)
  k_rmsnorm<<<16384, 256, 0, stream>>>(outp, mlp_w, xb);
  // 10. g = h2 @ gate^T
  gemm_bt<0><<<dim3(128,22), 256, 0, stream>>>(xb, 1024, wb_gate, 1024, gbuf, 2816, nullptr, 1024);
  // 11. g = silu(g) * (h2 @ up^T)
  gemm_bt<4><<<dim3(128,22), 256, 0, stream>>>(xb, 1024, wb_up, 1024, gbuf, 2816, nullptr, 1024);
  // 12. d_out += g @ down^T
  gemm_bt<5><<<dim3(128,8), 256, 0, stream>>>(gbuf, 2816, wb_down, 2816, outp, 1024, nullptr, 2816);
}

// Round 3
// 1615.490 us; speedup vs baseline: 1.4221x; 1.4221x over previous
//
#include <hip/hip_runtime.h>
#include <math.h>

typedef __bf16 bf16;
typedef __bf16 bf16x8 __attribute__((ext_vector_type(8)));
typedef float f32x4 __attribute__((ext_vector_type(4)));

#define DEVI static __device__ __forceinline__

DEVI float b2f(bf16 x){ return (float)x; }
DEVI bf16  f2b(float x){ return (bf16)x; }
DEVI float siluf_(float x){ return x / (1.f + __expf(-x)); }

DEVI void gload_lds16(const void* g, void* l){
  __builtin_amdgcn_global_load_lds((const __attribute__((address_space(1))) void*)g,
                                   (__attribute__((address_space(3))) void*)l, 16, 0, 0);
}

// ---------------------------------------------------------------------------
// C = A * W^T, A (M x K) bf16 row-major (lda), W (N x K) bf16 row-major (ldw).
// 128x128 tile, BK=64, 4 waves (2x2), 16x16x32 bf16 MFMA, global_load_lds.
// Epilogues: 0 bf16 | 1 fp32 | 2 softplus(acc+aux[col])->bf16
//            3 fp32 acc+aux[idx] | 4 C=silu(C)*acc (bf16, in place) | 5 C+=acc (fp32)
// ---------------------------------------------------------------------------
template<int EPI>
__global__ __launch_bounds__(256)
void gemm_bt(const bf16* __restrict__ A, int lda,
             const bf16* __restrict__ W, int ldw,
             void* __restrict__ Cp, int ldc,
             const float* __restrict__ aux, int K)
{
  __shared__ __align__(16) bf16 As[128*64];
  __shared__ __align__(16) bf16 Bs[128*64];
  const int tid  = threadIdx.x;
  const int lane = tid & 63;
  const int wid  = tid >> 6;
  const int srow = tid >> 3;          // 0..31
  const int scol = (tid & 7) << 3;    // 0..56

  const bf16* Ag = A + (long)blockIdx.x*128*lda + (long)srow*lda + scol;
  const bf16* Wg = W + (long)blockIdx.y*128*ldw + (long)srow*ldw + scol;
  bf16* Asd = &As[tid*8];
  bf16* Bsd = &Bs[tid*8];

  f32x4 acc[4][4];
#pragma unroll
  for (int i2=0;i2<4;i2++)
#pragma unroll
    for (int j2=0;j2<4;j2++) acc[i2][j2] = {0.f,0.f,0.f,0.f};

  const int wr = (wid>>1)<<6;
  const int wc = (wid&1)<<6;
  const int fr = lane & 15;
  const int fq = lane >> 4;

  for (int k0=0; k0<K; k0+=64){
    __syncthreads();
#pragma unroll
    for (int is=0; is<4; is++){
      gload_lds16(Ag + (long)is*32*lda + k0, Asd + is*2048);
      gload_lds16(Wg + (long)is*32*ldw + k0, Bsd + is*2048);
    }
    __syncthreads();
#pragma unroll
    for (int kk=0; kk<2; kk++){
      bf16x8 av[4], bv[4];
#pragma unroll
      for (int mi=0; mi<4; mi++)
        av[mi] = *(const bf16x8*)&As[(wr + mi*16 + fr)*64 + kk*32 + fq*8];
#pragma unroll
      for (int nj=0; nj<4; nj++)
        bv[nj] = *(const bf16x8*)&Bs[(wc + nj*16 + fr)*64 + kk*32 + fq*8];
#pragma unroll
      for (int mi=0; mi<4; mi++)
#pragma unroll
        for (int nj=0; nj<4; nj++)
          acc[mi][nj] = __builtin_amdgcn_mfma_f32_16x16x32_bf16(av[mi], bv[nj], acc[mi][nj], 0, 0, 0);
    }
  }

  const int row0 = (blockIdx.x<<7) + wr + (fq<<2);
  const int col0 = (blockIdx.y<<7) + wc + fr;
#pragma unroll
  for (int mi=0; mi<4; mi++){
#pragma unroll
    for (int nj=0; nj<4; nj++){
#pragma unroll
      for (int r=0; r<4; r++){
        const int row = row0 + mi*16 + r;
        const int col = col0 + nj*16;
        const long idx = (long)row*ldc + col;
        const float v = acc[mi][nj][r];
        if constexpr (EPI==0){ ((bf16*)Cp)[idx] = f2b(v); }
        else if constexpr (EPI==1){ ((float*)Cp)[idx] = v; }
        else if constexpr (EPI==2){
          float t = v + aux[col];
          ((bf16*)Cp)[idx] = f2b(t > 20.f ? t : log1pf(__expf(t)));
        }
        else if constexpr (EPI==3){ ((float*)Cp)[idx] = v + aux[idx]; }
        else if constexpr (EPI==4){
          bf16* g = (bf16*)Cp;
          g[idx] = f2b(siluf_(b2f(g[idx])) * v);
        }
        else { float* o = (float*)Cp; o[idx] += v; }
      }
    }
  }
}

__global__ void k_convert(const float* __restrict__ src, bf16* __restrict__ dst,
                          int n_dst, int n_src){
  int i = blockIdx.x*256 + threadIdx.x;
  if (i < n_dst) dst[i] = (i < n_src) ? f2b(src[i]) : f2b(0.f);
}

// RMSNorm over rows of 1024 fp32 -> bf16
__global__ __launch_bounds__(256)
void k_rmsnorm(const float* __restrict__ x, const float* __restrict__ w,
               bf16* __restrict__ out){
  const int row = blockIdx.x;
  const float4 v = ((const float4*)(x + (long)row*1024))[threadIdx.x];
  float ss = v.x*v.x + v.y*v.y + v.z*v.z + v.w*v.w;
#pragma unroll
  for (int off=32; off; off>>=1) ss += __shfl_down(ss, off);
  __shared__ float ps[4];
  if ((threadIdx.x & 63) == 0) ps[threadIdx.x>>6] = ss;
  __syncthreads();
  const float tot = ps[0]+ps[1]+ps[2]+ps[3];
  const float scale = rsqrtf(tot*(1.f/1024.f) + 1e-5f);
  const float4 wv = ((const float4*)w)[threadIdx.x];
  bf16* o = out + (long)row*1024 + threadIdx.x*4;
  o[0]=f2b(v.x*scale*wv.x); o[1]=f2b(v.y*scale*wv.y);
  o[2]=f2b(v.z*scale*wv.z); o[3]=f2b(v.w*scale*wv.w);
}

// causal depthwise conv (K=4) + bias + SiLU over xiraw (BT x 2048)
__global__ __launch_bounds__(256)
void k_conv(const bf16* __restrict__ xiraw, const float* __restrict__ cw,
            const float* __restrict__ cb, bf16* __restrict__ out){
  const long gid = (long)blockIdx.x*256 + threadIdx.x;   // BT*I
  const int i = (int)(gid & 2047);
  const long rowg = gid >> 11;
  const int t = (int)(rowg & 2047);
  float acc = cb[i];
#pragma unroll
  for (int k=0;k<4;k++){
    const int tt = t + k - 3;
    if (tt >= 0)
      acc = fmaf(b2f(xiraw[(rowg + k - 3)*2048 + i]), cw[i*4+k], acc);
  }
  out[gid] = f2b(siluf_(acc));
}

// sp[:, 0:64] fp32 -> bf16
__global__ void k_dtr(const float* __restrict__ sp, bf16* __restrict__ dtr){
  int idx = blockIdx.x*256 + threadIdx.x;   // BT*64
  dtr[idx] = f2b(sp[(long)(idx>>6)*128 + (idx&63)]);
}

// -------------------- chunked parallel scan (C=16, L=128) ------------------
#define NCHUNK 16
#define CLEN   128

// Pass A: per-chunk local scan (s0=0). Writes F[blk][n][lane] and SDT[blk][lane].
__global__ __launch_bounds__(64)
void k_scanA(const bf16* __restrict__ dt, const bf16* __restrict__ xi,
             const float* __restrict__ sp, const float* __restrict__ A_log,
             float* __restrict__ F, float* __restrict__ SDT)
{
  const int tid = threadIdx.x;
  const int blk = blockIdx.x;              // ((b*32+g)*16 + c)
  const int c = blk & 15;
  const int g = (blk >> 4) & 31;
  const int b = blk >> 9;
  const int i = (g << 6) + tid;
  float Ar[16], s[16];
#pragma unroll
  for (int n=0;n<16;n++){ Ar[n] = -__expf(A_log[i*16+n]); s[n]=0.f; }
  float sdt = 0.f;
  __shared__ float Bs[64][16];
  for (int tc=0; tc<CLEN/64; tc++){
    const int rowbase = b*2048 + c*CLEN + tc*64;
    __syncthreads();
#pragma unroll
    for (int j=0;j<16;j++){
      const int idx = (j<<6) + tid;        // 1024 floats
      Bs[idx>>4][idx&15] = sp[(long)(rowbase + (idx>>4))*128 + 64 + (idx&15)];
    }
    __syncthreads();
    for (int tt=0; tt<64; tt+=4){
      float dtv[4], xv[4];
#pragma unroll
      for (int j2=0;j2<4;j2++){
        const long gg = (long)(rowbase+tt+j2)*2048 + i;
        dtv[j2] = b2f(dt[gg]); xv[j2] = b2f(xi[gg]);
      }
#pragma unroll
      for (int j2=0;j2<4;j2++){
        sdt += dtv[j2];
        const float dx = dtv[j2]*xv[j2];
#pragma unroll
        for (int n=0;n<16;n++)
          s[n] = fmaf(__expf(dtv[j2]*Ar[n]), s[n], dx*Bs[tt+j2][n]);
      }
    }
  }
#pragma unroll
  for (int n=0;n<16;n++) F[((long)blk*16 + n)*64 + tid] = s[n];
  SDT[(long)blk*64 + tid] = sdt;
}

// Pass B: sequential combine over chunks; rewrites F in place as chunk-start
// state S0 (F[c] := state at start of chunk c).
__global__ __launch_bounds__(256)
void k_scanB(float* __restrict__ F, const float* __restrict__ SDT,
             const float* __restrict__ A_log)
{
  const int t = blockIdx.x*256 + threadIdx.x;    // B*32*16*64
  const int lane = t & 63;
  const int n = (t >> 6) & 15;
  const int g = (t >> 10) & 31;
  const int b = t >> 15;
  const int i = (g << 6) + lane;
  const float Ar = -__expf(A_log[i*16+n]);
  const long base = ((long)(b*32+g))*NCHUNK;
  float s0 = 0.f;
#pragma unroll
  for (int c=0;c<NCHUNK;c++){
    const long fidx = ((base + c)*16 + n)*64 + lane;
    const float f = F[fidx];
    const float p = __expf(Ar * SDT[(base + c)*64 + lane]);
    F[fidx] = s0;
    s0 = f + p*s0;
  }
}

// Pass C: per-chunk scan seeded with S0, fused (y+xi*D)*silu(gate) epilogue.
__global__ __launch_bounds__(64)
void k_scanC(const bf16* __restrict__ dt, bf16* __restrict__ xiy,
             const float* __restrict__ sp, const float* __restrict__ A_log,
             const bf16* __restrict__ gate, const float* __restrict__ Dw,
             const float* __restrict__ S0)
{
  const int tid = threadIdx.x;
  const int blk = blockIdx.x;
  const int c = blk & 15;
  const int g = (blk >> 4) & 31;
  const int b = blk >> 9;
  const int i = (g << 6) + tid;
  const float Di = Dw[i];
  float Ar[16], s[16];
#pragma unroll
  for (int n=0;n<16;n++){
    Ar[n] = -__expf(A_log[i*16+n]);
    s[n] = S0[((long)blk*16 + n)*64 + tid];
  }
  __shared__ float BCs[64][32];
  for (int tc=0; tc<CLEN/64; tc++){
    const int rowbase = b*2048 + c*CLEN + tc*64;
    __syncthreads();
#pragma unroll
    for (int j=0;j<32;j++){
      const int idx = (j<<6) + tid;        // 2048 floats
      BCs[idx>>5][idx&31] = sp[(long)(rowbase + (idx>>5))*128 + 64 + (idx&31)];
    }
    __syncthreads();
    for (int tt=0; tt<64; tt+=4){
      float dtv[4], xv[4], gv[4];
#pragma unroll
      for (int j2=0;j2<4;j2++){
        const long gg = (long)(rowbase+tt+j2)*2048 + i;
        dtv[j2] = b2f(dt[gg]); xv[j2] = b2f(xiy[gg]); gv[j2] = b2f(gate[gg]);
      }
#pragma unroll
      for (int j2=0;j2<4;j2++){
        const float dx = dtv[j2]*xv[j2];
        float yv = 0.f;
#pragma unroll
        for (int n=0;n<16;n++){
          s[n] = fmaf(__expf(dtv[j2]*Ar[n]), s[n], dx*BCs[tt+j2][n]);
          yv = fmaf(s[n], BCs[tt+j2][16+n], yv);
        }
        xiy[(long)(rowbase+tt+j2)*2048 + i] = f2b((yv + xv[j2]*Di) * siluf_(gv[j2]));
      }
    }
  }
}

extern "C" void kernel_launch(void* const* d_in, const int* in_sizes, int n_in,
                              void* d_out, int out_size, void* d_ws, size_t ws_size,
                              hipStream_t stream)
{
  const float* x         = (const float*)d_in[0];
  const float* mixer_w   = (const float*)d_in[1];
  const float* in_proj_w = (const float*)d_in[2];
  const float* conv_w    = (const float*)d_in[3];
  const float* conv_b    = (const float*)d_in[4];
  const float* x_proj_w  = (const float*)d_in[5];
  const float* dt_proj_w = (const float*)d_in[6];
  const float* dt_proj_b = (const float*)d_in[7];
  const float* A_log     = (const float*)d_in[8];
  const float* Dv        = (const float*)d_in[9];
  const float* out_proj_w= (const float*)d_in[10];
  const float* mlp_w     = (const float*)d_in[11];
  const float* gate_w    = (const float*)d_in[12];
  const float* up_w      = (const float*)d_in[13];
  const float* down_w    = (const float*)d_in[14];
  float* outp = (float*)d_out;

  char* p = (char*)d_ws;
  auto alloc = [&](size_t n){ char* r = p; p += (n + 255) & ~(size_t)255; return (void*)r; };
  bf16* wb_in   = (bf16*)alloc((size_t)4096*1024*2);
  bf16* wb_xp   = (bf16*)alloc((size_t)128*2048*2);
  bf16* wb_dt   = (bf16*)alloc((size_t)2048*64*2);
  bf16* wb_out  = (bf16*)alloc((size_t)1024*2048*2);
  bf16* wb_gate = (bf16*)alloc((size_t)2816*1024*2);
  bf16* wb_up   = (bf16*)alloc((size_t)2816*1024*2);
  bf16* wb_down = (bf16*)alloc((size_t)1024*2816*2);
  char* r1      = (char*)alloc((size_t)32<<20);   // xb | sp+dtr | F/SDT
  char* r2      = (char*)alloc((size_t)64<<20);   // xiraw | dtb
  char* r3      = (char*)alloc((size_t)64<<20);   // gateb | gbuf[0:64M)
  char* r4      = (char*)alloc((size_t)64<<20);   // xiconv->y | gbuf[64M:88M)
  if ((size_t)(p - (char*)d_ws) > ws_size) return;  // diagnostic guard

  bf16*  xb     = (bf16*)r1;
  float* sp     = (float*)r1;                       // 8 MB (xb dead by then)
  bf16*  dtr    = (bf16*)(r1 + (8<<20));            // 2 MB
  float* Fbuf   = (float*)(r1 + (10<<20));          // 16.8 MB (B*32*16 blk *16n*64)
  float* SDT    = (float*)(r1 + (28<<20));          // 1.05 MB
  bf16*  xiraw  = (bf16*)r2;
  bf16*  dtb    = (bf16*)r2;
  bf16*  gateb  = (bf16*)r3;
  bf16*  xiconv = (bf16*)r4;
  bf16*  gbuf   = (bf16*)r3;                        // 88 MB spans r3+r4

  auto cv = [&](const float* s_, bf16* d_, int nd, int ns){
    k_convert<<<dim3((nd+255)/256), dim3(256), 0, stream>>>(s_, d_, nd, ns);
  };
  cv(in_proj_w,  wb_in,   4096*1024, 4096*1024);
  cv(x_proj_w,   wb_xp,   128*2048,  96*2048);
  cv(dt_proj_w,  wb_dt,   2048*64,   2048*64);
  cv(out_proj_w, wb_out,  1024*2048, 1024*2048);
  cv(gate_w,     wb_gate, 2816*1024, 2816*1024);
  cv(up_w,       wb_up,   2816*1024, 2816*1024);
  cv(down_w,     wb_down, 1024*2816, 1024*2816);

  // 1. h = rmsnorm(x)
  k_rmsnorm<<<16384, 256, 0, stream>>>(x, mixer_w, xb);
  // 2. xi / gate halves of in_proj
  gemm_bt<0><<<dim3(128,16), 256, 0, stream>>>(xb, 1024, wb_in,             1024, xiraw, 2048, nullptr, 1024);
  gemm_bt<0><<<dim3(128,16), 256, 0, stream>>>(xb, 1024, wb_in + 2048*1024, 1024, gateb, 2048, nullptr, 1024);
  // 3. conv + silu
  k_conv<<<131072, 256, 0, stream>>>(xiraw, conv_w, conv_b, xiconv);
  // 4. sp = xiconv @ x_proj^T (padded to 128, fp32)
  gemm_bt<1><<<dim3(128,1), 256, 0, stream>>>(xiconv, 2048, wb_xp, 2048, sp, 128, nullptr, 2048);
  // 5. dt_r
  k_dtr<<<4096, 256, 0, stream>>>(sp, dtr);
  // 6. dt = softplus(dt_r @ dt_proj^T + b)
  gemm_bt<2><<<dim3(128,16), 256, 0, stream>>>(dtr, 64, wb_dt, 64, dtb, 2048, dt_proj_b, 64);
  // 7. chunked scan: A (local) -> B (combine) -> C (seeded + fused gating)
  k_scanA<<<4096, 64, 0, stream>>>(dtb, xiconv, sp, A_log, Fbuf, SDT);
  k_scanB<<<1024, 256, 0, stream>>>(Fbuf, SDT, A_log);
  k_scanC<<<4096, 64, 0, stream>>>(dtb, xiconv, sp, A_log, gateb, Dv, Fbuf);
  // 8. x2 = x + y @ out_proj^T -> d_out
  gemm_bt<3><<<dim3(128,8), 256, 0, stream>>>(xiconv, 2048, wb_out, 2048, outp, 1024, x, 2048);
  // 9. h2 = rmsnorm(x2)
  k_rmsnorm<<<16384, 256, 0, stream>>>(outp, mlp_w, xb);
  // 10. g = h2 @ gate^T
  gemm_bt<0><<<dim3(128,22), 256, 0, stream>>>(xb, 1024, wb_gate, 1024, gbuf, 2816, nullptr, 1024);
  // 11. g = silu(g) * (h2 @ up^T)
  gemm_bt<4><<<dim3(128,22), 256, 0, stream>>>(xb, 1024, wb_up, 1024, gbuf, 2816, nullptr, 1024);
  // 12. d_out += g @ down^T
  gemm_bt<5><<<dim3(128,8), 256, 0, stream>>>(gbuf, 2816, wb_down, 2816, outp, 1024, nullptr, 2816);
}

// Round 4
// 1384.709 us; speedup vs baseline: 1.6591x; 1.1667x over previous
//
#include <hip/hip_runtime.h>
#include <math.h>

typedef __bf16 bf16;
typedef __bf16 bf16x8 __attribute__((ext_vector_type(8)));
typedef float f32x4 __attribute__((ext_vector_type(4)));

#define DEVI static __device__ __forceinline__

DEVI float b2f(bf16 x){ return (float)x; }
DEVI bf16  f2b(float x){ return (bf16)x; }
DEVI float siluf_(float x){ return x / (1.f + __expf(-x)); }

DEVI void gload_lds16(const void* g, void* l){
  __builtin_amdgcn_global_load_lds((const __attribute__((address_space(1))) void*)g,
                                   (__attribute__((address_space(3))) void*)l, 16, 0, 0);
}

// ---------------------------------------------------------------------------
// gemm256: C = A * W^T. 256x256 tile, BK=64, 8 waves (2Mx4N), double-buffered
// LDS, prefetch-before-compute, one barrier per K-step. LDS chunk-XOR swizzle
// (j ^= row&7 on 16B chunks) applied on the GLOBAL source side (write stays
// linear for global_load_lds) and on the ds_read side. Requires M%256==0,
// N%256==0, K%64==0.
// Epilogues: 0 bf16 | 2 softplus(acc+aux[col])->bf16 | 3 fp32 acc+aux[idx]
//            4 C=silu(C)*acc (bf16 in place) | 5 C+=acc (fp32)
// ---------------------------------------------------------------------------
template<int EPI>
__global__ __launch_bounds__(512, 2)
void gemm256(const bf16* __restrict__ A, int lda,
             const bf16* __restrict__ W, int ldw,
             void* __restrict__ Cp, int ldc,
             const float* __restrict__ aux, int K)
{
  __shared__ __align__(16) bf16 As[2][256*64];
  __shared__ __align__(16) bf16 Bs[2][256*64];
  const int tid  = threadIdx.x;
  const int lane = tid & 63;
  const int wid  = tid >> 6;          // 0..7

  // staging sources: 4 16B chunks each for A and B per thread, source-swizzled
  const bf16* aG[4]; const bf16* bG[4];
  int dstofs[4];
#pragma unroll
  for (int is=0; is<4; is++){
    const int ci  = is*512 + tid;       // chunk id 0..2047
    const int row = ci >> 3;            // 0..255
    const int jl  = (ci & 7) ^ (row & 7);  // logical 16B chunk for this slot
    aG[is] = A + (long)(blockIdx.x*256 + row)*lda + jl*8;
    bG[is] = W + (long)(blockIdx.y*256 + row)*ldw + jl*8;
    dstofs[is] = ci*8;                  // element offset in LDS buffer (linear)
  }

  f32x4 acc[8][4];
#pragma unroll
  for (int i2=0;i2<8;i2++)
#pragma unroll
    for (int j2=0;j2<4;j2++) acc[i2][j2] = {0.f,0.f,0.f,0.f};

  const int wr = (wid>>2)<<7;   // 0 / 128
  const int wc = (wid&3)<<6;    // 0..192
  const int fr = lane & 15;
  const int fq = lane >> 4;     // 0..3
  const int rs = fr & 7;        // read-side swizzle key (row&7)

  // prologue: stage K-tile 0 into buf 0
#pragma unroll
  for (int is=0; is<4; is++){
    gload_lds16(aG[is], &As[0][dstofs[is]]);
    gload_lds16(bG[is], &Bs[0][dstofs[is]]);
  }
  __syncthreads();

  const int nt = K >> 6;
  int cur = 0;
  for (int t=0; t<nt; ++t){
    if (t+1 < nt){
      const long k1 = (long)(t+1) << 6;
#pragma unroll
      for (int is=0; is<4; is++){
        gload_lds16(aG[is] + k1, &As[cur^1][dstofs[is]]);
        gload_lds16(bG[is] + k1, &Bs[cur^1][dstofs[is]]);
      }
    }
#pragma unroll
    for (int kk=0; kk<2; kk++){
      const int jsw = (((kk<<2)|fq) ^ rs) << 3;   // swizzled element offset
      bf16x8 av[8], bv[4];
#pragma unroll
      for (int mi=0; mi<8; mi++)
        av[mi] = *(const bf16x8*)&As[cur][(wr + mi*16 + fr)*64 + jsw];
#pragma unroll
      for (int nj=0; nj<4; nj++)
        bv[nj] = *(const bf16x8*)&Bs[cur][(wc + nj*16 + fr)*64 + jsw];
#pragma unroll
      for (int mi=0; mi<8; mi++)
#pragma unroll
        for (int nj=0; nj<4; nj++)
          acc[mi][nj] = __builtin_amdgcn_mfma_f32_16x16x32_bf16(av[mi], bv[nj], acc[mi][nj], 0, 0, 0);
    }
    __syncthreads();   // drains prefetch (vmcnt0) + lgkm; protects buf reuse
    cur ^= 1;
  }

  const int row0 = (blockIdx.x<<8) + wr + (fq<<2);
  const int col0 = (blockIdx.y<<8) + wc + fr;
#pragma unroll
  for (int mi=0; mi<8; mi++){
#pragma unroll
    for (int nj=0; nj<4; nj++){
#pragma unroll
      for (int r=0; r<4; r++){
        const int row = row0 + mi*16 + r;
        const int col = col0 + nj*16;
        const long idx = (long)row*ldc + col;
        const float v = acc[mi][nj][r];
        if constexpr (EPI==0){ ((bf16*)Cp)[idx] = f2b(v); }
        else if constexpr (EPI==2){
          float tt = v + aux[col];
          ((bf16*)Cp)[idx] = f2b(tt > 20.f ? tt : log1pf(__expf(tt)));
        }
        else if constexpr (EPI==3){ ((float*)Cp)[idx] = v + aux[idx]; }
        else if constexpr (EPI==4){
          bf16* g = (bf16*)Cp;
          g[idx] = f2b(siluf_(b2f(g[idx])) * v);
        }
        else { float* o = (float*)Cp; o[idx] += v; }
      }
    }
  }
}

// ---------------------------------------------------------------------------
// legacy 128x128 GEMM (kept for x_proj, N=128). EPI: 1 = fp32 store.
// ---------------------------------------------------------------------------
template<int EPI>
__global__ __launch_bounds__(256)
void gemm_bt(const bf16* __restrict__ A, int lda,
             const bf16* __restrict__ W, int ldw,
             void* __restrict__ Cp, int ldc,
             const float* __restrict__ aux, int K)
{
  __shared__ __align__(16) bf16 As[128*64];
  __shared__ __align__(16) bf16 Bs[128*64];
  const int tid  = threadIdx.x;
  const int lane = tid & 63;
  const int wid  = tid >> 6;
  const int srow = tid >> 3;
  const int scol = (tid & 7) << 3;

  const bf16* Ag = A + (long)blockIdx.x*128*lda + (long)srow*lda + scol;
  const bf16* Wg = W + (long)blockIdx.y*128*ldw + (long)srow*ldw + scol;
  bf16* Asd = &As[tid*8];
  bf16* Bsd = &Bs[tid*8];

  f32x4 acc[4][4];
#pragma unroll
  for (int i2=0;i2<4;i2++)
#pragma unroll
    for (int j2=0;j2<4;j2++) acc[i2][j2] = {0.f,0.f,0.f,0.f};

  const int wr = (wid>>1)<<6;
  const int wc = (wid&1)<<6;
  const int fr = lane & 15;
  const int fq = lane >> 4;

  for (int k0=0; k0<K; k0+=64){
    __syncthreads();
#pragma unroll
    for (int is=0; is<4; is++){
      gload_lds16(Ag + (long)is*32*lda + k0, Asd + is*2048);
      gload_lds16(Wg + (long)is*32*ldw + k0, Bsd + is*2048);
    }
    __syncthreads();
#pragma unroll
    for (int kk=0; kk<2; kk++){
      bf16x8 av[4], bv[4];
#pragma unroll
      for (int mi=0; mi<4; mi++)
        av[mi] = *(const bf16x8*)&As[(wr + mi*16 + fr)*64 + kk*32 + fq*8];
#pragma unroll
      for (int nj=0; nj<4; nj++)
        bv[nj] = *(const bf16x8*)&Bs[(wc + nj*16 + fr)*64 + kk*32 + fq*8];
#pragma unroll
      for (int mi=0; mi<4; mi++)
#pragma unroll
        for (int nj=0; nj<4; nj++)
          acc[mi][nj] = __builtin_amdgcn_mfma_f32_16x16x32_bf16(av[mi], bv[nj], acc[mi][nj], 0, 0, 0);
    }
  }

  const int row0 = (blockIdx.x<<7) + wr + (fq<<2);
  const int col0 = (blockIdx.y<<7) + wc + fr;
#pragma unroll
  for (int mi=0; mi<4; mi++){
#pragma unroll
    for (int nj=0; nj<4; nj++){
#pragma unroll
      for (int r=0; r<4; r++){
        const int row = row0 + mi*16 + r;
        const int col = col0 + nj*16;
        const long idx = (long)row*ldc + col;
        const float v = acc[mi][nj][r];
        if constexpr (EPI==1){ ((float*)Cp)[idx] = v; }
        else { ((bf16*)Cp)[idx] = f2b(v); }
      }
    }
  }
}

__global__ void k_convert(const float* __restrict__ src, bf16* __restrict__ dst,
                          int n_dst, int n_src){
  int i = blockIdx.x*256 + threadIdx.x;
  if (i < n_dst) dst[i] = (i < n_src) ? f2b(src[i]) : f2b(0.f);
}

// RMSNorm over rows of 1024 fp32 -> bf16
__global__ __launch_bounds__(256)
void k_rmsnorm(const float* __restrict__ x, const float* __restrict__ w,
               bf16* __restrict__ out){
  const int row = blockIdx.x;
  const float4 v = ((const float4*)(x + (long)row*1024))[threadIdx.x];
  float ss = v.x*v.x + v.y*v.y + v.z*v.z + v.w*v.w;
#pragma unroll
  for (int off=32; off; off>>=1) ss += __shfl_down(ss, off);
  __shared__ float ps[4];
  if ((threadIdx.x & 63) == 0) ps[threadIdx.x>>6] = ss;
  __syncthreads();
  const float tot = ps[0]+ps[1]+ps[2]+ps[3];
  const float scale = rsqrtf(tot*(1.f/1024.f) + 1e-5f);
  const float4 wv = ((const float4*)w)[threadIdx.x];
  bf16* o = out + (long)row*1024 + threadIdx.x*4;
  o[0]=f2b(v.x*scale*wv.x); o[1]=f2b(v.y*scale*wv.y);
  o[2]=f2b(v.z*scale*wv.z); o[3]=f2b(v.w*scale*wv.w);
}

// causal depthwise conv (K=4) + bias + SiLU over xiraw (BT x 2048)
__global__ __launch_bounds__(256)
void k_conv(const bf16* __restrict__ xiraw, const float* __restrict__ cw,
            const float* __restrict__ cb, bf16* __restrict__ out){
  const long gid = (long)blockIdx.x*256 + threadIdx.x;
  const int i = (int)(gid & 2047);
  const long rowg = gid >> 11;
  const int t = (int)(rowg & 2047);
  float acc = cb[i];
#pragma unroll
  for (int k=0;k<4;k++){
    const int tt = t + k - 3;
    if (tt >= 0)
      acc = fmaf(b2f(xiraw[(rowg + k - 3)*2048 + i]), cw[i*4+k], acc);
  }
  out[gid] = f2b(siluf_(acc));
}

// sp[:, 0:64] fp32 -> bf16
__global__ void k_dtr(const float* __restrict__ sp, bf16* __restrict__ dtr){
  int idx = blockIdx.x*256 + threadIdx.x;
  dtr[idx] = f2b(sp[(long)(idx>>6)*128 + (idx&63)]);
}

// -------------------- chunked parallel scan (C=16, L=128) ------------------
#define NCHUNK 16
#define CLEN   128

__global__ __launch_bounds__(64)
void k_scanA(const bf16* __restrict__ dt, const bf16* __restrict__ xi,
             const float* __restrict__ sp, const float* __restrict__ A_log,
             float* __restrict__ F, float* __restrict__ SDT)
{
  const int tid = threadIdx.x;
  const int blk = blockIdx.x;
  const int c = blk & 15;
  const int g = (blk >> 4) & 31;
  const int b = blk >> 9;
  const int i = (g << 6) + tid;
  float Ar[16], s[16];
#pragma unroll
  for (int n=0;n<16;n++){ Ar[n] = -__expf(A_log[i*16+n]); s[n]=0.f; }
  float sdt = 0.f;
  __shared__ float Bsm[64][16];
  for (int tc=0; tc<CLEN/64; tc++){
    const int rowbase = b*2048 + c*CLEN + tc*64;
    __syncthreads();
#pragma unroll
    for (int j=0;j<16;j++){
      const int idx = (j<<6) + tid;
      Bsm[idx>>4][idx&15] = sp[(long)(rowbase + (idx>>4))*128 + 64 + (idx&15)];
    }
    __syncthreads();
    for (int tt=0; tt<64; tt+=4){
      float dtv[4], xv[4];
#pragma unroll
      for (int j2=0;j2<4;j2++){
        const long gg = (long)(rowbase+tt+j2)*2048 + i;
        dtv[j2] = b2f(dt[gg]); xv[j2] = b2f(xi[gg]);
      }
#pragma unroll
      for (int j2=0;j2<4;j2++){
        sdt += dtv[j2];
        const float dx = dtv[j2]*xv[j2];
#pragma unroll
        for (int n=0;n<16;n++)
          s[n] = fmaf(__expf(dtv[j2]*Ar[n]), s[n], dx*Bsm[tt+j2][n]);
      }
    }
  }
#pragma unroll
  for (int n=0;n<16;n++) F[((long)blk*16 + n)*64 + tid] = s[n];
  SDT[(long)blk*64 + tid] = sdt;
}

__global__ __launch_bounds__(256)
void k_scanB(float* __restrict__ F, const float* __restrict__ SDT,
             const float* __restrict__ A_log)
{
  const int t = blockIdx.x*256 + threadIdx.x;
  const int lane = t & 63;
  const int n = (t >> 6) & 15;
  const int g = (t >> 10) & 31;
  const int b = t >> 15;
  const int i = (g << 6) + lane;
  const float Ar = -__expf(A_log[i*16+n]);
  const long base = ((long)(b*32+g))*NCHUNK;
  float s0 = 0.f;
#pragma unroll
  for (int c=0;c<NCHUNK;c++){
    const long fidx = ((base + c)*16 + n)*64 + lane;
    const float f = F[fidx];
    const float p = __expf(Ar * SDT[(base + c)*64 + lane]);
    F[fidx] = s0;
    s0 = f + p*s0;
  }
}

__global__ __launch_bounds__(64)
void k_scanC(const bf16* __restrict__ dt, bf16* __restrict__ xiy,
             const float* __restrict__ sp, const float* __restrict__ A_log,
             const bf16* __restrict__ gate, const float* __restrict__ Dw,
             const float* __restrict__ S0)
{
  const int tid = threadIdx.x;
  const int blk = blockIdx.x;
  const int c = blk & 15;
  const int g = (blk >> 4) & 31;
  const int b = blk >> 9;
  const int i = (g << 6) + tid;
  const float Di = Dw[i];
  float Ar[16], s[16];
#pragma unroll
  for (int n=0;n<16;n++){
    Ar[n] = -__expf(A_log[i*16+n]);
    s[n] = S0[((long)blk*16 + n)*64 + tid];
  }
  __shared__ float BCs[64][32];
  for (int tc=0; tc<CLEN/64; tc++){
    const int rowbase = b*2048 + c*CLEN + tc*64;
    __syncthreads();
#pragma unroll
    for (int j=0;j<32;j++){
      const int idx = (j<<6) + tid;
      BCs[idx>>5][idx&31] = sp[(long)(rowbase + (idx>>5))*128 + 64 + (idx&31)];
    }
    __syncthreads();
    for (int tt=0; tt<64; tt+=4){
      float dtv[4], xv[4], gv[4];
#pragma unroll
      for (int j2=0;j2<4;j2++){
        const long gg = (long)(rowbase+tt+j2)*2048 + i;
        dtv[j2] = b2f(dt[gg]); xv[j2] = b2f(xiy[gg]); gv[j2] = b2f(gate[gg]);
      }
#pragma unroll
      for (int j2=0;j2<4;j2++){
        const float dx = dtv[j2]*xv[j2];
        float yv = 0.f;
#pragma unroll
        for (int n=0;n<16;n++){
          s[n] = fmaf(__expf(dtv[j2]*Ar[n]), s[n], dx*BCs[tt+j2][n]);
          yv = fmaf(s[n], BCs[tt+j2][16+n], yv);
        }
        xiy[(long)(rowbase+tt+j2)*2048 + i] = f2b((yv + xv[j2]*Di) * siluf_(gv[j2]));
      }
    }
  }
}

extern "C" void kernel_launch(void* const* d_in, const int* in_sizes, int n_in,
                              void* d_out, int out_size, void* d_ws, size_t ws_size,
                              hipStream_t stream)
{
  const float* x         = (const float*)d_in[0];
  const float* mixer_w   = (const float*)d_in[1];
  const float* in_proj_w = (const float*)d_in[2];
  const float* conv_w    = (const float*)d_in[3];
  const float* conv_b    = (const float*)d_in[4];
  const float* x_proj_w  = (const float*)d_in[5];
  const float* dt_proj_w = (const float*)d_in[6];
  const float* dt_proj_b = (const float*)d_in[7];
  const float* A_log     = (const float*)d_in[8];
  const float* Dv        = (const float*)d_in[9];
  const float* out_proj_w= (const float*)d_in[10];
  const float* mlp_w     = (const float*)d_in[11];
  const float* gate_w    = (const float*)d_in[12];
  const float* up_w      = (const float*)d_in[13];
  const float* down_w    = (const float*)d_in[14];
  float* outp = (float*)d_out;

  char* p = (char*)d_ws;
  auto alloc = [&](size_t n){ char* r = p; p += (n + 255) & ~(size_t)255; return (void*)r; };
  bf16* wb_in   = (bf16*)alloc((size_t)4096*1024*2);
  bf16* wb_xp   = (bf16*)alloc((size_t)128*2048*2);
  bf16* wb_dt   = (bf16*)alloc((size_t)2048*64*2);
  bf16* wb_out  = (bf16*)alloc((size_t)1024*2048*2);
  bf16* wb_gate = (bf16*)alloc((size_t)2816*1024*2);
  bf16* wb_up   = (bf16*)alloc((size_t)2816*1024*2);
  bf16* wb_down = (bf16*)alloc((size_t)1024*2816*2);
  char* r1      = (char*)alloc((size_t)32<<20);
  char* r2      = (char*)alloc((size_t)64<<20);
  char* r3      = (char*)alloc((size_t)64<<20);
  char* r4      = (char*)alloc((size_t)64<<20);
  if ((size_t)(p - (char*)d_ws) > ws_size) return;

  bf16*  xb     = (bf16*)r1;
  float* sp     = (float*)r1;
  bf16*  dtr    = (bf16*)(r1 + (8<<20));
  float* Fbuf   = (float*)(r1 + (10<<20));
  float* SDT    = (float*)(r1 + (28<<20));
  bf16*  xiraw  = (bf16*)r2;
  bf16*  dtb    = (bf16*)r2;
  bf16*  gateb  = (bf16*)r3;
  bf16*  xiconv = (bf16*)r4;
  bf16*  gbuf   = (bf16*)r3;

  auto cv = [&](const float* s_, bf16* d_, int nd, int ns){
    k_convert<<<dim3((nd+255)/256), dim3(256), 0, stream>>>(s_, d_, nd, ns);
  };
  cv(in_proj_w,  wb_in,   4096*1024, 4096*1024);
  cv(x_proj_w,   wb_xp,   128*2048,  96*2048);
  cv(dt_proj_w,  wb_dt,   2048*64,   2048*64);
  cv(out_proj_w, wb_out,  1024*2048, 1024*2048);
  cv(gate_w,     wb_gate, 2816*1024, 2816*1024);
  cv(up_w,       wb_up,   2816*1024, 2816*1024);
  cv(down_w,     wb_down, 1024*2816, 1024*2816);

  // 1. h = rmsnorm(x)
  k_rmsnorm<<<16384, 256, 0, stream>>>(x, mixer_w, xb);
  // 2. xi / gate halves of in_proj (256x256 tiles)
  gemm256<0><<<dim3(64,8), 512, 0, stream>>>(xb, 1024, wb_in,             1024, xiraw, 2048, nullptr, 1024);
  gemm256<0><<<dim3(64,8), 512, 0, stream>>>(xb, 1024, wb_in + 2048*1024, 1024, gateb, 2048, nullptr, 1024);
  // 3. conv + silu
  k_conv<<<131072, 256, 0, stream>>>(xiraw, conv_w, conv_b, xiconv);
  // 4. sp = xiconv @ x_proj^T (N=128 -> legacy kernel, fp32 out)
  gemm_bt<1><<<dim3(128,1), 256, 0, stream>>>(xiconv, 2048, wb_xp, 2048, sp, 128, nullptr, 2048);
  // 5. dt_r
  k_dtr<<<4096, 256, 0, stream>>>(sp, dtr);
  // 6. dt = softplus(dt_r @ dt_proj^T + b)
  gemm256<2><<<dim3(64,8), 512, 0, stream>>>(dtr, 64, wb_dt, 64, dtb, 2048, dt_proj_b, 64);
  // 7. chunked scan
  k_scanA<<<4096, 64, 0, stream>>>(dtb, xiconv, sp, A_log, Fbuf, SDT);
  k_scanB<<<1024, 256, 0, stream>>>(Fbuf, SDT, A_log);
  k_scanC<<<4096, 64, 0, stream>>>(dtb, xiconv, sp, A_log, gateb, Dv, Fbuf);
  // 8. x2 = x + y @ out_proj^T -> d_out
  gemm256<3><<<dim3(64,4), 512, 0, stream>>>(xiconv, 2048, wb_out, 2048, outp, 1024, x, 2048);
  // 9. h2 = rmsnorm(x2)
  k_rmsnorm<<<16384, 256, 0, stream>>>(outp, mlp_w, xb);
  // 10. g = h2 @ gate^T
  gemm256<0><<<dim3(64,11), 512, 0, stream>>>(xb, 1024, wb_gate, 1024, gbuf, 2816, nullptr, 1024);
  // 11. g = silu(g) * (h2 @ up^T)
  gemm256<4><<<dim3(64,11), 512, 0, stream>>>(xb, 1024, wb_up, 1024, gbuf, 2816, nullptr, 1024);
  // 12. d_out += g @ down^T
  gemm256<5><<<dim3(64,4), 512, 0, stream>>>(gbuf, 2816, wb_down, 2816, outp, 1024, nullptr, 2816);
}

// Round 5
// 1329.474 us; speedup vs baseline: 1.7280x; 1.0415x over previous
//
#include <hip/hip_runtime.h>
#include <math.h>

typedef __bf16 bf16;
typedef __bf16 bf16x8 __attribute__((ext_vector_type(8)));
typedef float f32x4 __attribute__((ext_vector_type(4)));

#define DEVI static __device__ __forceinline__

DEVI float b2f(bf16 x){ return (float)x; }
DEVI bf16  f2b(float x){ return (bf16)x; }
DEVI float siluf_(float x){ return x / (1.f + __expf(-x)); }

DEVI void gload_lds16(const void* g, void* l){
  __builtin_amdgcn_global_load_lds((const __attribute__((address_space(1))) void*)g,
                                   (__attribute__((address_space(3))) void*)l, 16, 0, 0);
}

#define SFENCE __builtin_amdgcn_sched_barrier(0)
#define BARX   do{ SFENCE; __builtin_amdgcn_s_barrier(); SFENCE; }while(0)
#define LGKM0  do{ asm volatile("s_waitcnt lgkmcnt(0)" ::: "memory"); SFENCE; }while(0)
#define VMC4   do{ asm volatile("s_waitcnt vmcnt(4)"   ::: "memory"); SFENCE; }while(0)
#define VMC0   do{ asm volatile("s_waitcnt vmcnt(0)"   ::: "memory"); SFENCE; }while(0)
#define MFMA_  __builtin_amdgcn_mfma_f32_16x16x32_bf16

// ---------------------------------------------------------------------------
// gemm8p: C = A * W^T. 256x256 tile, BK=64, 8 waves (2Mx4N), 8-phase schedule
// (T3+T4 counted vmcnt + T5 setprio), both-sides chunk-XOR LDS swizzle (T2),
// XCD-chunked block remap (T1). Tile t lives in buf (t&1); half-tiles staged
// per phase; vmcnt(4) only at phases 4/8 (vmcnt(0) in tail iteration).
// Requires M%256==0, N%256==0, K%128==0, grid count %8==0 for remap.
// Epilogues: 0 bf16 | 3 fp32 acc+aux[idx] | 4 C=silu(C)*acc bf16 | 5 C+=acc fp32
// ---------------------------------------------------------------------------
template<int EPI>
__global__ __launch_bounds__(512, 2)
void gemm8p(const bf16* __restrict__ A, int lda,
            const bf16* __restrict__ W, int ldw,
            void* __restrict__ Cp, int ldc,
            const float* __restrict__ aux, int K)
{
  __shared__ __align__(16) bf16 As[2][256*64];
  __shared__ __align__(16) bf16 Bs[2][256*64];
  const int tid  = threadIdx.x;
  const int lane = tid & 63;
  const int wid  = tid >> 6;

  // XCD-chunked remap (contiguous grid chunk per XCD)
  const int nwg = gridDim.x * gridDim.y;
  int lin = blockIdx.y * gridDim.x + blockIdx.x;
  if ((nwg & 7) == 0) lin = (lin & 7) * (nwg >> 3) + (lin >> 3);
  const int bx = lin & (gridDim.x - 1);     // gridDim.x is 64 (pow2)
  const int by = lin / gridDim.x;

  // staging addresses: per half-tile, 2 x 16B chunks per thread, source-swizzled
  const bf16* aRow[2]; const bf16* bRow[2]; int dste[2];
#pragma unroll
  for (int l=0;l<2;l++){
    const int ci = l*512 + tid;            // 0..1023 within half-tile
    const int r  = ci >> 3;                // 0..127
    const int jl = (ci & 7) ^ (r & 7);     // logical chunk for this slot
    aRow[l] = A + (long)(bx*256 + r)*lda + jl*8;
    bRow[l] = W + (long)(by*256 + r)*ldw + jl*8;
    dste[l] = ci*8;
  }
  auto stageA = [&](int buf, int half, int kt){
    const long ko = ((long)kt << 6) + (long)half*128*lda;
#pragma unroll
    for (int l=0;l<2;l++)
      gload_lds16(aRow[l] + ko, &As[buf][half*8192 + dste[l]]);
  };
  auto stageB = [&](int buf, int half, int kt){
    const long ko = ((long)kt << 6) + (long)half*128*ldw;
#pragma unroll
    for (int l=0;l<2;l++)
      gload_lds16(bRow[l] + ko, &Bs[buf][half*8192 + dste[l]]);
  };

  const int wr = (wid>>2)<<7;   // 0/128
  const int wc = (wid&3)<<6;    // 0..192
  const int fr = lane & 15;
  const int fq = lane >> 4;
  const int rs = fr & 7;
  const int jsw0 = ((fq  ) ^ rs) << 3;
  const int jsw1 = ((4|fq) ^ rs) << 3;

  f32x4 acc[8][4];
#pragma unroll
  for (int i2=0;i2<8;i2++)
#pragma unroll
    for (int j2=0;j2<4;j2++) acc[i2][j2] = {0.f,0.f,0.f,0.f};

  bf16x8 aLo[4][2], aHi[4][2], bLo[2][2], bHi[2][2];

#define LD_A(dst, B, mio) \
  _Pragma("unroll") for (int m=0;m<4;m++){ \
    dst[m][0]=*(const bf16x8*)&As[B][(wr+(m+mio)*16+fr)*64+jsw0]; \
    dst[m][1]=*(const bf16x8*)&As[B][(wr+(m+mio)*16+fr)*64+jsw1]; }
#define LD_B(dst, B, njo) \
  _Pragma("unroll") for (int n=0;n<2;n++){ \
    dst[n][0]=*(const bf16x8*)&Bs[B][(wc+(n+njo)*16+fr)*64+jsw0]; \
    dst[n][1]=*(const bf16x8*)&Bs[B][(wc+(n+njo)*16+fr)*64+jsw1]; }
#define MMAQ(aF, bF, mio, njo) \
  __builtin_amdgcn_s_setprio(1); \
  _Pragma("unroll") for (int m=0;m<4;m++) \
  _Pragma("unroll") for (int n=0;n<2;n++){ \
    acc[m+mio][n+njo]=MFMA_(aF[m][0],bF[n][0],acc[m+mio][n+njo],0,0,0); \
    acc[m+mio][n+njo]=MFMA_(aF[m][1],bF[n][1],acc[m+mio][n+njo],0,0,0); } \
  __builtin_amdgcn_s_setprio(0);

  // prologue: tile0 fully into buf0; tile1's B halves into buf1
  stageA(0,0,0); stageA(0,1,0); stageB(0,0,0); stageB(0,1,0);
  stageB(1,0,1); stageB(1,1,1);
  VMC4; BARX;                       // tile0 landed; tile1-B may be in flight

  const int half = K >> 7;          // iterations (2 K-tiles each)
  for (int j=0; j<half; ++j){
    const int t1 = 2*j+1, n0 = 2*j+2, n1 = 2*j+3;
    const bool more = (j+1 < half);
    // p1
    LD_A(aLo,0,0); LD_B(bLo,0,0);
    stageA(1,0,t1);
    BARX; LGKM0; MMAQ(aLo,bLo,0,0); BARX;
    // p2
    LD_B(bHi,0,2);
    stageA(1,1,t1);
    BARX; LGKM0; MMAQ(aLo,bHi,0,2); BARX;
    // p3
    LD_A(aHi,0,4);
    if (more) stageB(0,0,n0);
    BARX; LGKM0; MMAQ(aHi,bLo,4,0); BARX;
    // p4
    if (more){ stageB(0,1,n0); VMC4; } else { VMC0; }
    BARX; MMAQ(aHi,bHi,4,2); BARX;
    // p5
    LD_A(aLo,1,0); LD_B(bLo,1,0);
    if (more) stageA(0,0,n0);
    BARX; LGKM0; MMAQ(aLo,bLo,0,0); BARX;
    // p6
    LD_B(bHi,1,2);
    if (more) stageA(0,1,n0);
    BARX; LGKM0; MMAQ(aLo,bHi,0,2); BARX;
    // p7
    LD_A(aHi,1,4);
    if (more) stageB(1,0,n1);
    BARX; LGKM0; MMAQ(aHi,bLo,4,0); BARX;
    // p8
    if (more){ stageB(1,1,n1); VMC4; }
    BARX; MMAQ(aHi,bHi,4,2); BARX;
  }

  const int row0 = (bx<<8) + wr + (fq<<2);
  const int col0 = (by<<8) + wc + fr;
#pragma unroll
  for (int mi=0; mi<8; mi++){
#pragma unroll
    for (int nj=0; nj<4; nj++){
#pragma unroll
      for (int r=0; r<4; r++){
        const int row = row0 + mi*16 + r;
        const int col = col0 + nj*16;
        const long idx = (long)row*ldc + col;
        const float v = acc[mi][nj][r];
        if constexpr (EPI==0){ ((bf16*)Cp)[idx] = f2b(v); }
        else if constexpr (EPI==3){ ((float*)Cp)[idx] = v + aux[idx]; }
        else if constexpr (EPI==4){
          bf16* g = (bf16*)Cp;
          g[idx] = f2b(siluf_(b2f(g[idx])) * v);
        }
        else { float* o = (float*)Cp; o[idx] += v; }
      }
    }
  }
#undef LD_A
#undef LD_B
#undef MMAQ
}

// ---------------------------------------------------------------------------
// legacy 128x128 GEMM (x_proj N=128, dt_proj K=64).
// EPI: 1 fp32 | 2 softplus(acc+aux[col])->bf16
// ---------------------------------------------------------------------------
template<int EPI>
__global__ __launch_bounds__(256)
void gemm_bt(const bf16* __restrict__ A, int lda,
             const bf16* __restrict__ W, int ldw,
             void* __restrict__ Cp, int ldc,
             const float* __restrict__ aux, int K)
{
  __shared__ __align__(16) bf16 As[128*64];
  __shared__ __align__(16) bf16 Bs[128*64];
  const int tid  = threadIdx.x;
  const int lane = tid & 63;
  const int wid  = tid >> 6;
  const int srow = tid >> 3;
  const int scol = (tid & 7) << 3;

  const bf16* Ag = A + (long)blockIdx.x*128*lda + (long)srow*lda + scol;
  const bf16* Wg = W + (long)blockIdx.y*128*ldw + (long)srow*ldw + scol;
  bf16* Asd = &As[tid*8];
  bf16* Bsd = &Bs[tid*8];

  f32x4 acc[4][4];
#pragma unroll
  for (int i2=0;i2<4;i2++)
#pragma unroll
    for (int j2=0;j2<4;j2++) acc[i2][j2] = {0.f,0.f,0.f,0.f};

  const int wr = (wid>>1)<<6;
  const int wc = (wid&1)<<6;
  const int fr = lane & 15;
  const int fq = lane >> 4;

  for (int k0=0; k0<K; k0+=64){
    __syncthreads();
#pragma unroll
    for (int is=0; is<4; is++){
      gload_lds16(Ag + (long)is*32*lda + k0, Asd + is*2048);
      gload_lds16(Wg + (long)is*32*ldw + k0, Bsd + is*2048);
    }
    __syncthreads();
#pragma unroll
    for (int kk=0; kk<2; kk++){
      bf16x8 av[4], bv[4];
#pragma unroll
      for (int mi=0; mi<4; mi++)
        av[mi] = *(const bf16x8*)&As[(wr + mi*16 + fr)*64 + kk*32 + fq*8];
#pragma unroll
      for (int nj=0; nj<4; nj++)
        bv[nj] = *(const bf16x8*)&Bs[(wc + nj*16 + fr)*64 + kk*32 + fq*8];
#pragma unroll
      for (int mi=0; mi<4; mi++)
#pragma unroll
        for (int nj=0; nj<4; nj++)
          acc[mi][nj] = MFMA_(av[mi], bv[nj], acc[mi][nj], 0, 0, 0);
    }
  }

  const int row0 = (blockIdx.x<<7) + wr + (fq<<2);
  const int col0 = (blockIdx.y<<7) + wc + fr;
#pragma unroll
  for (int mi=0; mi<4; mi++){
#pragma unroll
    for (int nj=0; nj<4; nj++){
#pragma unroll
      for (int r=0; r<4; r++){
        const int row = row0 + mi*16 + r;
        const int col = col0 + nj*16;
        const long idx = (long)row*ldc + col;
        const float v = acc[mi][nj][r];
        if constexpr (EPI==1){ ((float*)Cp)[idx] = v; }
        else if constexpr (EPI==2){
          float t = v + aux[col];
          ((bf16*)Cp)[idx] = f2b(t > 20.f ? t : log1pf(__expf(t)));
        }
        else { ((bf16*)Cp)[idx] = f2b(v); }
      }
    }
  }
}

__global__ void k_convert(const float* __restrict__ src, bf16* __restrict__ dst,
                          int n_dst, int n_src){
  int i = blockIdx.x*256 + threadIdx.x;
  if (i < n_dst) dst[i] = (i < n_src) ? f2b(src[i]) : f2b(0.f);
}

// RMSNorm over rows of 1024 fp32 -> bf16
__global__ __launch_bounds__(256)
void k_rmsnorm(const float* __restrict__ x, const float* __restrict__ w,
               bf16* __restrict__ out){
  const int row = blockIdx.x;
  const float4 v = ((const float4*)(x + (long)row*1024))[threadIdx.x];
  float ss = v.x*v.x + v.y*v.y + v.z*v.z + v.w*v.w;
#pragma unroll
  for (int off=32; off; off>>=1) ss += __shfl_down(ss, off);
  __shared__ float ps[4];
  if ((threadIdx.x & 63) == 0) ps[threadIdx.x>>6] = ss;
  __syncthreads();
  const float tot = ps[0]+ps[1]+ps[2]+ps[3];
  const float scale = rsqrtf(tot*(1.f/1024.f) + 1e-5f);
  const float4 wv = ((const float4*)w)[threadIdx.x];
  bf16* o = out + (long)row*1024 + threadIdx.x*4;
  o[0]=f2b(v.x*scale*wv.x); o[1]=f2b(v.y*scale*wv.y);
  o[2]=f2b(v.z*scale*wv.z); o[3]=f2b(v.w*scale*wv.w);
}

// causal depthwise conv (K=4) + bias + SiLU over xiraw (BT x 2048)
__global__ __launch_bounds__(256)
void k_conv(const bf16* __restrict__ xiraw, const float* __restrict__ cw,
            const float* __restrict__ cb, bf16* __restrict__ out){
  const long gid = (long)blockIdx.x*256 + threadIdx.x;
  const int i = (int)(gid & 2047);
  const long rowg = gid >> 11;
  const int t = (int)(rowg & 2047);
  float acc = cb[i];
#pragma unroll
  for (int k=0;k<4;k++){
    const int tt = t + k - 3;
    if (tt >= 0)
      acc = fmaf(b2f(xiraw[(rowg + k - 3)*2048 + i]), cw[i*4+k], acc);
  }
  out[gid] = f2b(siluf_(acc));
}

// sp[:, 0:64] fp32 -> bf16
__global__ void k_dtr(const float* __restrict__ sp, bf16* __restrict__ dtr){
  int idx = blockIdx.x*256 + threadIdx.x;
  dtr[idx] = f2b(sp[(long)(idx>>6)*128 + (idx&63)]);
}

// -------------------- chunked parallel scan (C=16, L=128) ------------------
#define NCHUNK 16
#define CLEN   128

__global__ __launch_bounds__(64)
void k_scanA(const bf16* __restrict__ dt, const bf16* __restrict__ xi,
             const float* __restrict__ sp, const float* __restrict__ A_log,
             float* __restrict__ F, float* __restrict__ SDT)
{
  const int tid = threadIdx.x;
  const int blk = blockIdx.x;
  const int c = blk & 15;
  const int g = (blk >> 4) & 31;
  const int b = blk >> 9;
  const int i = (g << 6) + tid;
  float Ar[16], s[16];
#pragma unroll
  for (int n=0;n<16;n++){ Ar[n] = -__expf(A_log[i*16+n]); s[n]=0.f; }
  float sdt = 0.f;
  __shared__ float Bsm[64][16];
  for (int tc=0; tc<CLEN/64; tc++){
    const int rowbase = b*2048 + c*CLEN + tc*64;
    __syncthreads();
#pragma unroll
    for (int j=0;j<16;j++){
      const int idx = (j<<6) + tid;
      Bsm[idx>>4][idx&15] = sp[(long)(rowbase + (idx>>4))*128 + 64 + (idx&15)];
    }
    __syncthreads();
    for (int tt=0; tt<64; tt+=4){
      float dtv[4], xv[4];
#pragma unroll
      for (int j2=0;j2<4;j2++){
        const long gg = (long)(rowbase+tt+j2)*2048 + i;
        dtv[j2] = b2f(dt[gg]); xv[j2] = b2f(xi[gg]);
      }
#pragma unroll
      for (int j2=0;j2<4;j2++){
        sdt += dtv[j2];
        const float dx = dtv[j2]*xv[j2];
#pragma unroll
        for (int n=0;n<16;n++)
          s[n] = fmaf(__expf(dtv[j2]*Ar[n]), s[n], dx*Bsm[tt+j2][n]);
      }
    }
  }
#pragma unroll
  for (int n=0;n<16;n++) F[((long)blk*16 + n)*64 + tid] = s[n];
  SDT[(long)blk*64 + tid] = sdt;
}

__global__ __launch_bounds__(256)
void k_scanB(float* __restrict__ F, const float* __restrict__ SDT,
             const float* __restrict__ A_log)
{
  const int t = blockIdx.x*256 + threadIdx.x;
  const int lane = t & 63;
  const int n = (t >> 6) & 15;
  const int g = (t >> 10) & 31;
  const int b = t >> 15;
  const int i = (g << 6) + lane;
  const float Ar = -__expf(A_log[i*16+n]);
  const long base = ((long)(b*32+g))*NCHUNK;
  float s0 = 0.f;
#pragma unroll
  for (int c=0;c<NCHUNK;c++){
    const long fidx = ((base + c)*16 + n)*64 + lane;
    const float f = F[fidx];
    const float p = __expf(Ar * SDT[(base + c)*64 + lane]);
    F[fidx] = s0;
    s0 = f + p*s0;
  }
}

__global__ __launch_bounds__(64)
void k_scanC(const bf16* __restrict__ dt, bf16* __restrict__ xiy,
             const float* __restrict__ sp, const float* __restrict__ A_log,
             const bf16* __restrict__ gate, const float* __restrict__ Dw,
             const float* __restrict__ S0)
{
  const int tid = threadIdx.x;
  const int blk = blockIdx.x;
  const int c = blk & 15;
  const int g = (blk >> 4) & 31;
  const int b = blk >> 9;
  const int i = (g << 6) + tid;
  const float Di = Dw[i];
  float Ar[16], s[16];
#pragma unroll
  for (int n=0;n<16;n++){
    Ar[n] = -__expf(A_log[i*16+n]);
    s[n] = S0[((long)blk*16 + n)*64 + tid];
  }
  __shared__ float BCs[64][32];
  for (int tc=0; tc<CLEN/64; tc++){
    const int rowbase = b*2048 + c*CLEN + tc*64;
    __syncthreads();
#pragma unroll
    for (int j=0;j<32;j++){
      const int idx = (j<<6) + tid;
      BCs[idx>>5][idx&31] = sp[(long)(rowbase + (idx>>5))*128 + 64 + (idx&31)];
    }
    __syncthreads();
    for (int tt=0; tt<64; tt+=4){
      float dtv[4], xv[4], gv[4];
#pragma unroll
      for (int j2=0;j2<4;j2++){
        const long gg = (long)(rowbase+tt+j2)*2048 + i;
        dtv[j2] = b2f(dt[gg]); xv[j2] = b2f(xiy[gg]); gv[j2] = b2f(gate[gg]);
      }
#pragma unroll
      for (int j2=0;j2<4;j2++){
        const float dx = dtv[j2]*xv[j2];
        float yv = 0.f;
#pragma unroll
        for (int n=0;n<16;n++){
          s[n] = fmaf(__expf(dtv[j2]*Ar[n]), s[n], dx*BCs[tt+j2][n]);
          yv = fmaf(s[n], BCs[tt+j2][16+n], yv);
        }
        xiy[(long)(rowbase+tt+j2)*2048 + i] = f2b((yv + xv[j2]*Di) * siluf_(gv[j2]));
      }
    }
  }
}

extern "C" void kernel_launch(void* const* d_in, const int* in_sizes, int n_in,
                              void* d_out, int out_size, void* d_ws, size_t ws_size,
                              hipStream_t stream)
{
  const float* x         = (const float*)d_in[0];
  const float* mixer_w   = (const float*)d_in[1];
  const float* in_proj_w = (const float*)d_in[2];
  const float* conv_w    = (const float*)d_in[3];
  const float* conv_b    = (const float*)d_in[4];
  const float* x_proj_w  = (const float*)d_in[5];
  const float* dt_proj_w = (const float*)d_in[6];
  const float* dt_proj_b = (const float*)d_in[7];
  const float* A_log     = (const float*)d_in[8];
  const float* Dv        = (const float*)d_in[9];
  const float* out_proj_w= (const float*)d_in[10];
  const float* mlp_w     = (const float*)d_in[11];
  const float* gate_w    = (const float*)d_in[12];
  const float* up_w      = (const float*)d_in[13];
  const float* down_w    = (const float*)d_in[14];
  float* outp = (float*)d_out;

  char* p = (char*)d_ws;
  auto alloc = [&](size_t n){ char* r = p; p += (n + 255) & ~(size_t)255; return (void*)r; };
  bf16* wb_in   = (bf16*)alloc((size_t)4096*1024*2);
  bf16* wb_xp   = (bf16*)alloc((size_t)128*2048*2);
  bf16* wb_dt   = (bf16*)alloc((size_t)2048*64*2);
  bf16* wb_out  = (bf16*)alloc((size_t)1024*2048*2);
  bf16* wb_gate = (bf16*)alloc((size_t)2816*1024*2);
  bf16* wb_up   = (bf16*)alloc((size_t)2816*1024*2);
  bf16* wb_down = (bf16*)alloc((size_t)1024*2816*2);
  char* r1      = (char*)alloc((size_t)32<<20);
  char* r2      = (char*)alloc((size_t)64<<20);
  char* r3      = (char*)alloc((size_t)64<<20);
  char* r4      = (char*)alloc((size_t)64<<20);
  if ((size_t)(p - (char*)d_ws) > ws_size) return;

  bf16*  xb     = (bf16*)r1;
  float* sp     = (float*)r1;
  bf16*  dtr    = (bf16*)(r1 + (8<<20));
  float* Fbuf   = (float*)(r1 + (10<<20));
  float* SDT    = (float*)(r1 + (28<<20));
  bf16*  xiraw  = (bf16*)r2;
  bf16*  dtb    = (bf16*)r2;
  bf16*  gateb  = (bf16*)r3;
  bf16*  xiconv = (bf16*)r4;
  bf16*  gbuf   = (bf16*)r3;

  auto cv = [&](const float* s_, bf16* d_, int nd, int ns){
    k_convert<<<dim3((nd+255)/256), dim3(256), 0, stream>>>(s_, d_, nd, ns);
  };
  cv(in_proj_w,  wb_in,   4096*1024, 4096*1024);
  cv(x_proj_w,   wb_xp,   128*2048,  96*2048);
  cv(dt_proj_w,  wb_dt,   2048*64,   2048*64);
  cv(out_proj_w, wb_out,  1024*2048, 1024*2048);
  cv(gate_w,     wb_gate, 2816*1024, 2816*1024);
  cv(up_w,       wb_up,   2816*1024, 2816*1024);
  cv(down_w,     wb_down, 1024*2816, 1024*2816);

  // 1. h = rmsnorm(x)
  k_rmsnorm<<<16384, 256, 0, stream>>>(x, mixer_w, xb);
  // 2. xi / gate halves of in_proj (8-phase 256x256)
  gemm8p<0><<<dim3(64,8), 512, 0, stream>>>(xb, 1024, wb_in,             1024, xiraw, 2048, nullptr, 1024);
  gemm8p<0><<<dim3(64,8), 512, 0, stream>>>(xb, 1024, wb_in + 2048*1024, 1024, gateb, 2048, nullptr, 1024);
  // 3. conv + silu
  k_conv<<<131072, 256, 0, stream>>>(xiraw, conv_w, conv_b, xiconv);
  // 4. sp = xiconv @ x_proj^T (N=128 -> legacy kernel, fp32 out)
  gemm_bt<1><<<dim3(128,1), 256, 0, stream>>>(xiconv, 2048, wb_xp, 2048, sp, 128, nullptr, 2048);
  // 5. dt_r
  k_dtr<<<4096, 256, 0, stream>>>(sp, dtr);
  // 6. dt = softplus(dt_r @ dt_proj^T + b)  (K=64 -> legacy)
  gemm_bt<2><<<dim3(128,16), 256, 0, stream>>>(dtr, 64, wb_dt, 64, dtb, 2048, dt_proj_b, 64);
  // 7. chunked scan
  k_scanA<<<4096, 64, 0, stream>>>(dtb, xiconv, sp, A_log, Fbuf, SDT);
  k_scanB<<<1024, 256, 0, stream>>>(Fbuf, SDT, A_log);
  k_scanC<<<4096, 64, 0, stream>>>(dtb, xiconv, sp, A_log, gateb, Dv, Fbuf);
  // 8. x2 = x + y @ out_proj^T -> d_out
  gemm8p<3><<<dim3(64,4), 512, 0, stream>>>(xiconv, 2048, wb_out, 2048, outp, 1024, x, 2048);
  // 9. h2 = rmsnorm(x2)
  k_rmsnorm<<<16384, 256, 0, stream>>>(outp, mlp_w, xb);
  // 10. g = h2 @ gate^T
  gemm8p<0><<<dim3(64,11), 512, 0, stream>>>(xb, 1024, wb_gate, 1024, gbuf, 2816, nullptr, 1024);
  // 11. g = silu(g) * (h2 @ up^T)
  gemm8p<4><<<dim3(64,11), 512, 0, stream>>>(xb, 1024, wb_up, 1024, gbuf, 2816, nullptr, 1024);
  // 12. d_out += g @ down^T
  gemm8p<5><<<dim3(64,4), 512, 0, stream>>>(gbuf, 2816, wb_down, 2816, outp, 1024, nullptr, 2816);
}

// Round 6
// 1325.482 us; speedup vs baseline: 1.7333x; 1.0030x over previous
//
#include <hip/hip_runtime.h>
#include <math.h>

typedef __bf16 bf16;
typedef __bf16 bf16x8 __attribute__((ext_vector_type(8)));
typedef float f32x4 __attribute__((ext_vector_type(4)));

#define DEVI static __device__ __forceinline__

DEVI float b2f(bf16 x){ return (float)x; }
DEVI bf16  f2b(float x){ return (bf16)x; }
DEVI float siluf_(float x){ return x / (1.f + __expf(-x)); }

DEVI void gload_lds16(const void* g, void* l){
  __builtin_amdgcn_global_load_lds((const __attribute__((address_space(1))) void*)g,
                                   (__attribute__((address_space(3))) void*)l, 16, 0, 0);
}

#define BARX   __builtin_amdgcn_s_barrier()
#define VMC4   asm volatile("s_waitcnt vmcnt(4)" ::: "memory")
#define VMC0   asm volatile("s_waitcnt vmcnt(0)" ::: "memory")
#define MFMA_  __builtin_amdgcn_mfma_f32_16x16x32_bf16

// ---------------------------------------------------------------------------
// gemm8p: C = A * W^T. 256x256 tile, BK=64, 8 waves (2Mx4N), 8-phase schedule
// (counted vmcnt + setprio), both-sides chunk-XOR LDS swizzle, bx-chunked
// XCD mapping (XCD k owns bx in [8k,8k+8), by-major inside -> A chunk stays
// in that XCD's L2). No sched_barrier pinning (m141 lesson) — compiler
// schedules within phases; raw s_barrier delimits them.
// Requires gridDim.x==64, M%256==0, N%256==0, K%128==0, nwg%8==0.
// Epilogues: 0 bf16 | 3 fp32 acc+aux[idx] | 4 C=silu(C)*acc bf16 | 5 C+=acc fp32
// ---------------------------------------------------------------------------
template<int EPI>
__global__ __launch_bounds__(512, 2)
void gemm8p(const bf16* __restrict__ A, int lda,
            const bf16* __restrict__ W, int ldw,
            void* __restrict__ Cp, int ldc,
            const float* __restrict__ aux, int K)
{
  __shared__ __align__(16) bf16 As[2][256*64];
  __shared__ __align__(16) bf16 Bs[2][256*64];
  const int tid  = threadIdx.x;
  const int lane = tid & 63;
  const int wid  = tid >> 6;

  // bx-chunked XCD mapping (dispatch round-robins old%8 across XCDs)
  const int old = blockIdx.y * gridDim.x + blockIdx.x;
  const int bx = ((old & 7) << 3) | ((old >> 3) & 7);
  const int by = old >> 6;

  // staging addresses: per half-tile, 2 x 16B chunks per thread, source-swizzled
  const bf16* aRow[2]; const bf16* bRow[2]; int dste[2];
#pragma unroll
  for (int l=0;l<2;l++){
    const int ci = l*512 + tid;            // 0..1023 within half-tile
    const int r  = ci >> 3;                // 0..127
    const int jl = (ci & 7) ^ (r & 7);     // logical chunk for this slot
    aRow[l] = A + (long)(bx*256 + r)*lda + jl*8;
    bRow[l] = W + (long)(by*256 + r)*ldw + jl*8;
    dste[l] = ci*8;
  }
  auto stageA = [&](int buf, int half, int kt){
    const long ko = ((long)kt << 6) + (long)half*128*lda;
#pragma unroll
    for (int l=0;l<2;l++)
      gload_lds16(aRow[l] + ko, &As[buf][half*8192 + dste[l]]);
  };
  auto stageB = [&](int buf, int half, int kt){
    const long ko = ((long)kt << 6) + (long)half*128*ldw;
#pragma unroll
    for (int l=0;l<2;l++)
      gload_lds16(bRow[l] + ko, &Bs[buf][half*8192 + dste[l]]);
  };

  const int wr = (wid>>2)<<7;   // 0/128
  const int wc = (wid&3)<<6;    // 0..192
  const int fr = lane & 15;
  const int fq = lane >> 4;
  const int rs = fr & 7;
  const int jsw0 = ((fq  ) ^ rs) << 3;
  const int jsw1 = ((4|fq) ^ rs) << 3;

  f32x4 acc[8][4];
#pragma unroll
  for (int i2=0;i2<8;i2++)
#pragma unroll
    for (int j2=0;j2<4;j2++) acc[i2][j2] = {0.f,0.f,0.f,0.f};

  bf16x8 aLo[4][2], aHi[4][2], bLo[2][2], bHi[2][2];

#define LD_A(dst, B, mio) \
  _Pragma("unroll") for (int m=0;m<4;m++){ \
    dst[m][0]=*(const bf16x8*)&As[B][(wr+(m+mio)*16+fr)*64+jsw0]; \
    dst[m][1]=*(const bf16x8*)&As[B][(wr+(m+mio)*16+fr)*64+jsw1]; }
#define LD_B(dst, B, njo) \
  _Pragma("unroll") for (int n=0;n<2;n++){ \
    dst[n][0]=*(const bf16x8*)&Bs[B][(wc+(n+njo)*16+fr)*64+jsw0]; \
    dst[n][1]=*(const bf16x8*)&Bs[B][(wc+(n+njo)*16+fr)*64+jsw1]; }
#define MMAQ(aF, bF, mio, njo) \
  __builtin_amdgcn_s_setprio(1); \
  _Pragma("unroll") for (int m=0;m<4;m++) \
  _Pragma("unroll") for (int n=0;n<2;n++){ \
    acc[m+mio][n+njo]=MFMA_(aF[m][0],bF[n][0],acc[m+mio][n+njo],0,0,0); \
    acc[m+mio][n+njo]=MFMA_(aF[m][1],bF[n][1],acc[m+mio][n+njo],0,0,0); } \
  __builtin_amdgcn_s_setprio(0);

  // prologue: tile0 fully into buf0; tile1's B halves into buf1
  stageA(0,0,0); stageA(0,1,0); stageB(0,0,0); stageB(0,1,0);
  stageB(1,0,1); stageB(1,1,1);
  VMC4; BARX;                       // tile0 landed; tile1-B may be in flight

  const int half = K >> 7;          // iterations (2 K-tiles each)
  for (int j=0; j<half; ++j){
    const int t1 = 2*j+1, n0 = 2*j+2, n1 = 2*j+3;
    const bool more = (j+1 < half);
    // p1
    LD_A(aLo,0,0); LD_B(bLo,0,0);
    stageA(1,0,t1);
    BARX; MMAQ(aLo,bLo,0,0); BARX;
    // p2
    LD_B(bHi,0,2);
    stageA(1,1,t1);
    BARX; MMAQ(aLo,bHi,0,2); BARX;
    // p3
    LD_A(aHi,0,4);
    if (more) stageB(0,0,n0);
    BARX; MMAQ(aHi,bLo,4,0); BARX;
    // p4
    if (more){ stageB(0,1,n0); VMC4; } else { VMC0; }
    BARX; MMAQ(aHi,bHi,4,2); BARX;
    // p5
    LD_A(aLo,1,0); LD_B(bLo,1,0);
    if (more) stageA(0,0,n0);
    BARX; MMAQ(aLo,bLo,0,0); BARX;
    // p6
    LD_B(bHi,1,2);
    if (more) stageA(0,1,n0);
    BARX; MMAQ(aLo,bHi,0,2); BARX;
    // p7
    LD_A(aHi,1,4);
    if (more) stageB(1,0,n1);
    BARX; MMAQ(aHi,bLo,4,0); BARX;
    // p8
    if (more){ stageB(1,1,n1); VMC4; }
    BARX; MMAQ(aHi,bHi,4,2); BARX;
  }

  const int row0 = (bx<<8) + wr + (fq<<2);
  const int col0 = (by<<8) + wc + fr;
#pragma unroll
  for (int mi=0; mi<8; mi++){
#pragma unroll
    for (int nj=0; nj<4; nj++){
#pragma unroll
      for (int r=0; r<4; r++){
        const int row = row0 + mi*16 + r;
        const int col = col0 + nj*16;
        const long idx = (long)row*ldc + col;
        const float v = acc[mi][nj][r];
        if constexpr (EPI==0){ ((bf16*)Cp)[idx] = f2b(v); }
        else if constexpr (EPI==3){ ((float*)Cp)[idx] = v + aux[idx]; }
        else if constexpr (EPI==4){
          bf16* g = (bf16*)Cp;
          g[idx] = f2b(siluf_(b2f(g[idx])) * v);
        }
        else { float* o = (float*)Cp; o[idx] += v; }
      }
    }
  }
#undef LD_A
#undef LD_B
#undef MMAQ
}

// ---------------------------------------------------------------------------
// legacy 128x128 GEMM (x_proj N=128, dt_proj K=64).
// EPI: 1 fp32 | 2 softplus(acc+aux[col])->bf16
// ---------------------------------------------------------------------------
template<int EPI>
__global__ __launch_bounds__(256)
void gemm_bt(const bf16* __restrict__ A, int lda,
             const bf16* __restrict__ W, int ldw,
             void* __restrict__ Cp, int ldc,
             const float* __restrict__ aux, int K)
{
  __shared__ __align__(16) bf16 As[128*64];
  __shared__ __align__(16) bf16 Bs[128*64];
  const int tid  = threadIdx.x;
  const int lane = tid & 63;
  const int wid  = tid >> 6;
  const int srow = tid >> 3;
  const int scol = (tid & 7) << 3;

  const bf16* Ag = A + (long)blockIdx.x*128*lda + (long)srow*lda + scol;
  const bf16* Wg = W + (long)blockIdx.y*128*ldw + (long)srow*ldw + scol;
  bf16* Asd = &As[tid*8];
  bf16* Bsd = &Bs[tid*8];

  f32x4 acc[4][4];
#pragma unroll
  for (int i2=0;i2<4;i2++)
#pragma unroll
    for (int j2=0;j2<4;j2++) acc[i2][j2] = {0.f,0.f,0.f,0.f};

  const int wr = (wid>>1)<<6;
  const int wc = (wid&1)<<6;
  const int fr = lane & 15;
  const int fq = lane >> 4;

  for (int k0=0; k0<K; k0+=64){
    __syncthreads();
#pragma unroll
    for (int is=0; is<4; is++){
      gload_lds16(Ag + (long)is*32*lda + k0, Asd + is*2048);
      gload_lds16(Wg + (long)is*32*ldw + k0, Bsd + is*2048);
    }
    __syncthreads();
#pragma unroll
    for (int kk=0; kk<2; kk++){
      bf16x8 av[4], bv[4];
#pragma unroll
      for (int mi=0; mi<4; mi++)
        av[mi] = *(const bf16x8*)&As[(wr + mi*16 + fr)*64 + kk*32 + fq*8];
#pragma unroll
      for (int nj=0; nj<4; nj++)
        bv[nj] = *(const bf16x8*)&Bs[(wc + nj*16 + fr)*64 + kk*32 + fq*8];
#pragma unroll
      for (int mi=0; mi<4; mi++)
#pragma unroll
        for (int nj=0; nj<4; nj++)
          acc[mi][nj] = MFMA_(av[mi], bv[nj], acc[mi][nj], 0, 0, 0);
    }
  }

  const int row0 = (blockIdx.x<<7) + wr + (fq<<2);
  const int col0 = (blockIdx.y<<7) + wc + fr;
#pragma unroll
  for (int mi=0; mi<4; mi++){
#pragma unroll
    for (int nj=0; nj<4; nj++){
#pragma unroll
      for (int r=0; r<4; r++){
        const int row = row0 + mi*16 + r;
        const int col = col0 + nj*16;
        const long idx = (long)row*ldc + col;
        const float v = acc[mi][nj][r];
        if constexpr (EPI==1){ ((float*)Cp)[idx] = v; }
        else if constexpr (EPI==2){
          float t = v + aux[col];
          ((bf16*)Cp)[idx] = f2b(t > 20.f ? t : log1pf(__expf(t)));
        }
        else { ((bf16*)Cp)[idx] = f2b(v); }
      }
    }
  }
}

__global__ void k_convert(const float* __restrict__ src, bf16* __restrict__ dst,
                          int n_dst, int n_src){
  int i = blockIdx.x*256 + threadIdx.x;
  if (i < n_dst) dst[i] = (i < n_src) ? f2b(src[i]) : f2b(0.f);
}

// RMSNorm over rows of 1024 fp32 -> bf16
__global__ __launch_bounds__(256)
void k_rmsnorm(const float* __restrict__ x, const float* __restrict__ w,
               bf16* __restrict__ out){
  const int row = blockIdx.x;
  const float4 v = ((const float4*)(x + (long)row*1024))[threadIdx.x];
  float ss = v.x*v.x + v.y*v.y + v.z*v.z + v.w*v.w;
#pragma unroll
  for (int off=32; off; off>>=1) ss += __shfl_down(ss, off);
  __shared__ float ps[4];
  if ((threadIdx.x & 63) == 0) ps[threadIdx.x>>6] = ss;
  __syncthreads();
  const float tot = ps[0]+ps[1]+ps[2]+ps[3];
  const float scale = rsqrtf(tot*(1.f/1024.f) + 1e-5f);
  const float4 wv = ((const float4*)w)[threadIdx.x];
  bf16* o = out + (long)row*1024 + threadIdx.x*4;
  o[0]=f2b(v.x*scale*wv.x); o[1]=f2b(v.y*scale*wv.y);
  o[2]=f2b(v.z*scale*wv.z); o[3]=f2b(v.w*scale*wv.w);
}

// causal depthwise conv (K=4) + bias + SiLU over xiraw (BT x 2048)
__global__ __launch_bounds__(256)
void k_conv(const bf16* __restrict__ xiraw, const float* __restrict__ cw,
            const float* __restrict__ cb, bf16* __restrict__ out){
  const long gid = (long)blockIdx.x*256 + threadIdx.x;
  const int i = (int)(gid & 2047);
  const long rowg = gid >> 11;
  const int t = (int)(rowg & 2047);
  float acc = cb[i];
#pragma unroll
  for (int k=0;k<4;k++){
    const int tt = t + k - 3;
    if (tt >= 0)
      acc = fmaf(b2f(xiraw[(rowg + k - 3)*2048 + i]), cw[i*4+k], acc);
  }
  out[gid] = f2b(siluf_(acc));
}

// sp[:, 0:64] fp32 -> bf16
__global__ void k_dtr(const float* __restrict__ sp, bf16* __restrict__ dtr){
  int idx = blockIdx.x*256 + threadIdx.x;
  dtr[idx] = f2b(sp[(long)(idx>>6)*128 + (idx&63)]);
}

// -------------------- chunked parallel scan (C=16, L=128) ------------------
#define NCHUNK 16
#define CLEN   128

__global__ __launch_bounds__(64)
void k_scanA(const bf16* __restrict__ dt, const bf16* __restrict__ xi,
             const float* __restrict__ sp, const float* __restrict__ A_log,
             float* __restrict__ F, float* __restrict__ SDT)
{
  const int tid = threadIdx.x;
  const int blk = blockIdx.x;
  const int c = blk & 15;
  const int g = (blk >> 4) & 31;
  const int b = blk >> 9;
  const int i = (g << 6) + tid;
  float Ar[16], s[16];
#pragma unroll
  for (int n=0;n<16;n++){ Ar[n] = -__expf(A_log[i*16+n]); s[n]=0.f; }
  float sdt = 0.f;
  __shared__ float Bsm[64][16];
  for (int tc=0; tc<CLEN/64; tc++){
    const int rowbase = b*2048 + c*CLEN + tc*64;
    __syncthreads();
#pragma unroll
    for (int j=0;j<16;j++){
      const int idx = (j<<6) + tid;
      Bsm[idx>>4][idx&15] = sp[(long)(rowbase + (idx>>4))*128 + 64 + (idx&15)];
    }
    __syncthreads();
    for (int tt=0; tt<64; tt+=4){
      float dtv[4], xv[4];
#pragma unroll
      for (int j2=0;j2<4;j2++){
        const long gg = (long)(rowbase+tt+j2)*2048 + i;
        dtv[j2] = b2f(dt[gg]); xv[j2] = b2f(xi[gg]);
      }
#pragma unroll
      for (int j2=0;j2<4;j2++){
        sdt += dtv[j2];
        const float dx = dtv[j2]*xv[j2];
#pragma unroll
        for (int n=0;n<16;n++)
          s[n] = fmaf(__expf(dtv[j2]*Ar[n]), s[n], dx*Bsm[tt+j2][n]);
      }
    }
  }
#pragma unroll
  for (int n=0;n<16;n++) F[((long)blk*16 + n)*64 + tid] = s[n];
  SDT[(long)blk*64 + tid] = sdt;
}

__global__ __launch_bounds__(256)
void k_scanB(float* __restrict__ F, const float* __restrict__ SDT,
             const float* __restrict__ A_log)
{
  const int t = blockIdx.x*256 + threadIdx.x;
  const int lane = t & 63;
  const int n = (t >> 6) & 15;
  const int g = (t >> 10) & 31;
  const int b = t >> 15;
  const int i = (g << 6) + lane;
  const float Ar = -__expf(A_log[i*16+n]);
  const long base = ((long)(b*32+g))*NCHUNK;
  float s0 = 0.f;
#pragma unroll
  for (int c=0;c<NCHUNK;c++){
    const long fidx = ((base + c)*16 + n)*64 + lane;
    const float f = F[fidx];
    const float p = __expf(Ar * SDT[(base + c)*64 + lane]);
    F[fidx] = s0;
    s0 = f + p*s0;
  }
}

__global__ __launch_bounds__(64)
void k_scanC(const bf16* __restrict__ dt, bf16* __restrict__ xiy,
             const float* __restrict__ sp, const float* __restrict__ A_log,
             const bf16* __restrict__ gate, const float* __restrict__ Dw,
             const float* __restrict__ S0)
{
  const int tid = threadIdx.x;
  const int blk = blockIdx.x;
  const int c = blk & 15;
  const int g = (blk >> 4) & 31;
  const int b = blk >> 9;
  const int i = (g << 6) + tid;
  const float Di = Dw[i];
  float Ar[16], s[16];
#pragma unroll
  for (int n=0;n<16;n++){
    Ar[n] = -__expf(A_log[i*16+n]);
    s[n] = S0[((long)blk*16 + n)*64 + tid];
  }
  __shared__ float BCs[64][32];
  for (int tc=0; tc<CLEN/64; tc++){
    const int rowbase = b*2048 + c*CLEN + tc*64;
    __syncthreads();
#pragma unroll
    for (int j=0;j<32;j++){
      const int idx = (j<<6) + tid;
      BCs[idx>>5][idx&31] = sp[(long)(rowbase + (idx>>5))*128 + 64 + (idx&31)];
    }
    __syncthreads();
    for (int tt=0; tt<64; tt+=4){
      float dtv[4], xv[4], gv[4];
#pragma unroll
      for (int j2=0;j2<4;j2++){
        const long gg = (long)(rowbase+tt+j2)*2048 + i;
        dtv[j2] = b2f(dt[gg]); xv[j2] = b2f(xiy[gg]); gv[j2] = b2f(gate[gg]);
      }
#pragma unroll
      for (int j2=0;j2<4;j2++){
        const float dx = dtv[j2]*xv[j2];
        float yv = 0.f;
#pragma unroll
        for (int n=0;n<16;n++){
          s[n] = fmaf(__expf(dtv[j2]*Ar[n]), s[n], dx*BCs[tt+j2][n]);
          yv = fmaf(s[n], BCs[tt+j2][16+n], yv);
        }
        xiy[(long)(rowbase+tt+j2)*2048 + i] = f2b((yv + xv[j2]*Di) * siluf_(gv[j2]));
      }
    }
  }
}

extern "C" void kernel_launch(void* const* d_in, const int* in_sizes, int n_in,
                              void* d_out, int out_size, void* d_ws, size_t ws_size,
                              hipStream_t stream)
{
  const float* x         = (const float*)d_in[0];
  const float* mixer_w   = (const float*)d_in[1];
  const float* in_proj_w = (const float*)d_in[2];
  const float* conv_w    = (const float*)d_in[3];
  const float* conv_b    = (const float*)d_in[4];
  const float* x_proj_w  = (const float*)d_in[5];
  const float* dt_proj_w = (const float*)d_in[6];
  const float* dt_proj_b = (const float*)d_in[7];
  const float* A_log     = (const float*)d_in[8];
  const float* Dv        = (const float*)d_in[9];
  const float* out_proj_w= (const float*)d_in[10];
  const float* mlp_w     = (const float*)d_in[11];
  const float* gate_w    = (const float*)d_in[12];
  const float* up_w      = (const float*)d_in[13];
  const float* down_w    = (const float*)d_in[14];
  float* outp = (float*)d_out;

  char* p = (char*)d_ws;
  auto alloc = [&](size_t n){ char* r = p; p += (n + 255) & ~(size_t)255; return (void*)r; };
  bf16* wb_in   = (bf16*)alloc((size_t)4096*1024*2);
  bf16* wb_xp   = (bf16*)alloc((size_t)128*2048*2);
  bf16* wb_dt   = (bf16*)alloc((size_t)2048*64*2);
  bf16* wb_out  = (bf16*)alloc((size_t)1024*2048*2);
  bf16* wb_gate = (bf16*)alloc((size_t)2816*1024*2);
  bf16* wb_up   = (bf16*)alloc((size_t)2816*1024*2);
  bf16* wb_down = (bf16*)alloc((size_t)1024*2816*2);
  char* r1      = (char*)alloc((size_t)32<<20);
  char* r2      = (char*)alloc((size_t)64<<20);
  char* r3      = (char*)alloc((size_t)64<<20);
  char* r4      = (char*)alloc((size_t)64<<20);
  if ((size_t)(p - (char*)d_ws) > ws_size) return;

  bf16*  xb     = (bf16*)r1;
  float* sp     = (float*)r1;
  bf16*  dtr    = (bf16*)(r1 + (8<<20));
  float* Fbuf   = (float*)(r1 + (10<<20));
  float* SDT    = (float*)(r1 + (28<<20));
  bf16*  xiraw  = (bf16*)r2;
  bf16*  dtb    = (bf16*)r2;
  bf16*  gateb  = (bf16*)r3;
  bf16*  xiconv = (bf16*)r4;
  bf16*  gbuf   = (bf16*)r3;

  auto cv = [&](const float* s_, bf16* d_, int nd, int ns){
    k_convert<<<dim3((nd+255)/256), dim3(256), 0, stream>>>(s_, d_, nd, ns);
  };
  cv(in_proj_w,  wb_in,   4096*1024, 4096*1024);
  cv(x_proj_w,   wb_xp,   128*2048,  96*2048);
  cv(dt_proj_w,  wb_dt,   2048*64,   2048*64);
  cv(out_proj_w, wb_out,  1024*2048, 1024*2048);
  cv(gate_w,     wb_gate, 2816*1024, 2816*1024);
  cv(up_w,       wb_up,   2816*1024, 2816*1024);
  cv(down_w,     wb_down, 1024*2816, 1024*2816);

  // 1. h = rmsnorm(x)
  k_rmsnorm<<<16384, 256, 0, stream>>>(x, mixer_w, xb);
  // 2. xi / gate halves of in_proj (8-phase 256x256)
  gemm8p<0><<<dim3(64,8), 512, 0, stream>>>(xb, 1024, wb_in,             1024, xiraw, 2048, nullptr, 1024);
  gemm8p<0><<<dim3(64,8), 512, 0, stream>>>(xb, 1024, wb_in + 2048*1024, 1024, gateb, 2048, nullptr, 1024);
  // 3. conv + silu
  k_conv<<<131072, 256, 0, stream>>>(xiraw, conv_w, conv_b, xiconv);
  // 4. sp = xiconv @ x_proj^T (N=128 -> legacy kernel, fp32 out)
  gemm_bt<1><<<dim3(128,1), 256, 0, stream>>>(xiconv, 2048, wb_xp, 2048, sp, 128, nullptr, 2048);
  // 5. dt_r
  k_dtr<<<4096, 256, 0, stream>>>(sp, dtr);
  // 6. dt = softplus(dt_r @ dt_proj^T + b)  (K=64 -> legacy)
  gemm_bt<2><<<dim3(128,16), 256, 0, stream>>>(dtr, 64, wb_dt, 64, dtb, 2048, dt_proj_b, 64);
  // 7. chunked scan
  k_scanA<<<4096, 64, 0, stream>>>(dtb, xiconv, sp, A_log, Fbuf, SDT);
  k_scanB<<<1024, 256, 0, stream>>>(Fbuf, SDT, A_log);
  k_scanC<<<4096, 64, 0, stream>>>(dtb, xiconv, sp, A_log, gateb, Dv, Fbuf);
  // 8. x2 = x + y @ out_proj^T -> d_out
  gemm8p<3><<<dim3(64,4), 512, 0, stream>>>(xiconv, 2048, wb_out, 2048, outp, 1024, x, 2048);
  // 9. h2 = rmsnorm(x2)
  k_rmsnorm<<<16384, 256, 0, stream>>>(outp, mlp_w, xb);
  // 10. g = h2 @ gate^T
  gemm8p<0><<<dim3(64,11), 512, 0, stream>>>(xb, 1024, wb_gate, 1024, gbuf, 2816, nullptr, 1024);
  // 11. g = silu(g) * (h2 @ up^T)
  gemm8p<4><<<dim3(64,11), 512, 0, stream>>>(xb, 1024, wb_up, 1024, gbuf, 2816, nullptr, 1024);
  // 12. d_out += g @ down^T
  gemm8p<5><<<dim3(64,4), 512, 0, stream>>>(gbuf, 2816, wb_down, 2816, outp, 1024, nullptr, 2816);
}